// Round 4
// baseline (29958.133 us; speedup 1.0000x reference)
//
#include <hip/hip_runtime.h>
#include <stdint.h>

// 2-layer bidirectional LSTM, B=64 S=512 IN=512 H=512. I/O f32; MFMA operands bf16;
// gate math f32. Gate order i,f,g,o.
//
//  xg[d][g][m] = x[m] @ Wih_d^T  (MFMA GEMM, fused fw+bw via blockIdx.z), m = tt*64+b.
//  recurrence: 32 WGs (16/dir, 32 h-cols each, 2 waves); Whh slice register-resident;
//  h broadcast via bf16 ring hglob[2 slots]; per-dir counter barrier each step using
//  ONE release atomic-add + relaxed poll + ONE agent acquire fence (no threadfence).
//  Next-step xg/mask prefetched into registers before the barrier.
//
//  ws: [arrive 4096B][hglob 2*2*64*512*2B][cstate 2*64*512*4B (nch>1)]
//      [hs0 67MB (nch>1; else aliased into d_out)][xg_fw][xg_bw]

typedef short bf16x8 __attribute__((ext_vector_type(8)));
typedef float f32x4 __attribute__((ext_vector_type(4)));
typedef unsigned short u16;

template<int N> struct IC { static constexpr int value = N; };

__device__ __forceinline__ float bf2f(u16 u) {
  union { uint32_t i; float f; } v; v.i = ((uint32_t)u) << 16; return v.f;
}
__device__ __forceinline__ u16 f2bf(float f) {
  union { float f; uint32_t i; } v; v.f = f;
  uint32_t u = v.i;
  return (u16)((u + 0x7FFFu + ((u >> 16) & 1u)) >> 16);
}
__device__ __forceinline__ float sigf(float x) { return 1.0f / (1.0f + __expf(-x)); }
__device__ __forceinline__ float tanhf_(float x) { return 2.0f / (1.0f + __expf(-2.0f * x)) - 1.0f; }
__device__ __forceinline__ u16 u4get(ushort4 v, int r) {
  return r == 0 ? v.x : r == 1 ? v.y : r == 2 ? v.z : v.w;
}
__device__ __forceinline__ bf16x8 ld8f32(const float* p) {
  float4 a = *(const float4*)p;
  float4 b = *(const float4*)(p + 4);
  bf16x8 r;
  r[0] = (short)f2bf(a.x); r[1] = (short)f2bf(a.y);
  r[2] = (short)f2bf(a.z); r[3] = (short)f2bf(a.w);
  r[4] = (short)f2bf(b.x); r[5] = (short)f2bf(b.y);
  r[6] = (short)f2bf(b.z); r[7] = (short)f2bf(b.w);
  return r;
}

// ---------------- xg GEMM: xg[n][m-m_base] = sum_k A[m][k] * W[n][k] ----------------
// A[m][k] = Abuf[((m&63)*512 + (m>>6))*KDIM + k]; AF32=1: f32 (inputs), 0: bf16 (hs0).
// blockIdx.z selects direction (W, xg, m_base). grid (16, CM/128, 2), block 256.
template<int KDIM, int AF32>
__global__ __launch_bounds__(256) void xg_gemm(
    const void* __restrict__ Av,
    const float* __restrict__ Wfw, const float* __restrict__ Wbw,
    u16* __restrict__ xgf, u16* __restrict__ xgb,
    int mb_fw, int mb_bw, int CM)
{
  const int tid = threadIdx.x;
  const int l = tid & 63, w = tid >> 6;
  const int wm = w & 1, wn = w >> 1;
  const int z = blockIdx.z;
  const float* W = z ? Wbw : Wfw;
  u16* xg = z ? xgb : xgf;
  const int m_base = z ? mb_bw : mb_fw;
  const int m0 = m_base + blockIdx.y * 128 + wm * 64;
  const int n0 = blockIdx.x * 128 + wn * 64;

  const float* Af = (const float*)Av;
  const u16*   Au = (const u16*)Av;
  long aoff[4];
#pragma unroll
  for (int mt = 0; mt < 4; ++mt) {
    int m = m0 + mt * 16 + (l & 15);
    aoff[mt] = ((long)(m & 63) * 512 + (m >> 6)) * KDIM + ((l >> 4) * 8);
  }
  const float* brow[4];
#pragma unroll
  for (int nt = 0; nt < 4; ++nt) {
    int n = n0 + nt * 16 + (l & 15);
    brow[nt] = W + (long)n * KDIM + ((l >> 4) * 8);
  }
  f32x4 acc[4][4] = {};
  for (int kk = 0; kk < KDIM / 32; ++kk) {
    bf16x8 a[4], b[4];
#pragma unroll
    for (int mt = 0; mt < 4; ++mt) {
      if constexpr (AF32) a[mt] = ld8f32(Af + aoff[mt] + kk * 32);
      else                a[mt] = *(const bf16x8*)(Au + aoff[mt] + kk * 32);
    }
#pragma unroll
    for (int nt = 0; nt < 4; ++nt) b[nt] = ld8f32(brow[nt] + kk * 32);
#pragma unroll
    for (int mt = 0; mt < 4; ++mt)
#pragma unroll
      for (int nt = 0; nt < 4; ++nt)
        acc[mt][nt] = __builtin_amdgcn_mfma_f32_16x16x32_bf16(a[mt], b[nt], acc[mt][nt], 0, 0, 0);
  }
#pragma unroll
  for (int nt = 0; nt < 4; ++nt) {
    int n = n0 + nt * 16 + (l & 15);
    long cb = (long)n * CM;
#pragma unroll
    for (int mt = 0; mt < 4; ++mt) {
      int mr = (m0 - m_base) + mt * 16 + (l >> 4) * 4;
      ushort4 u;
      u.x = f2bf(acc[mt][nt][0]); u.y = f2bf(acc[mt][nt][1]);
      u.z = f2bf(acc[mt][nt][2]); u.w = f2bf(acc[mt][nt][3]);
      *(ushort4*)(xg + cb + mr) = u;
    }
  }
}

// ---------------- recurrence ----------------
// grid=32: d=blockIdx.x>>4, wg=blockIdx.x&15 (h-cols [wg*32,wg*32+32)). 2 waves/block.
__global__ __launch_bounds__(128, 1) void lstm_rec(
    const u16* __restrict__ xg_fw, const u16* __restrict__ xg_bw,
    int mb_fw, int mb_bw, int CM,
    const float* __restrict__ Whh_fw, const float* __restrict__ Whh_bw,
    const float* __restrict__ bih_fw, const float* __restrict__ bhh_fw,
    const float* __restrict__ bih_bw, const float* __restrict__ bhh_bw,
    const float* __restrict__ mask,
    u16* __restrict__ hs0, float* __restrict__ outF, int out_mode,
    float* __restrict__ hn, float* __restrict__ cn,
    float* __restrict__ cstate, u16* __restrict__ hglob,
    int t_begin, int t_end, int* __restrict__ arrive)
{
  const int tid = threadIdx.x;
  const int l = tid & 63;
  const int w = tid >> 6;
  const int d = blockIdx.x >> 4;
  const int wg = blockIdx.x & 15;
  const int j0 = wg * 32;

  const float* Whh = d ? Whh_bw : Whh_fw;
  const float* bih = d ? bih_bw : bih_fw;
  const float* bhh = d ? bhh_bw : bhh_fw;
  const u16* xgd = d ? xg_bw : xg_fw;
  const int m_base = d ? mb_bw : mb_fw;
  u16* hg = hglob + d * 2 * 32768;   // [2 slots][64][512]
  int* arr = arrive + d;

  __shared__ float ex[2][2][2][2][4][64];  // [srcwave][g2][ct][mtl][r][lane] = 16KB

  // Whh fragments (bf16): B-op[k][n]=Whh[n][k]; lane: col=l&15, k=(l>>4)*8+j
  bf16x8 Bf[2][2][16];
#pragma unroll
  for (int g2 = 0; g2 < 2; ++g2) {
#pragma unroll
    for (int ct = 0; ct < 2; ++ct) {
      const int grow = (w * 2 + g2) * 512 + j0 + ct * 16 + (l & 15);
      const float* p = Whh + (long)grow * 512 + ((l >> 4) * 8);
#pragma unroll
      for (int kk = 0; kk < 16; ++kk)
        Bf[g2][ct][kk] = ld8f32(p + kk * 32);
    }
  }
  float bsum[4][2];
#pragma unroll
  for (int q = 0; q < 4; ++q)
#pragma unroll
    for (int ct = 0; ct < 2; ++ct) {
      int g = q * 512 + j0 + ct * 16 + (l & 15);
      bsum[q][ct] = bih[g] + bhh[g];
    }

  float c_[2][2][4];
  float hl[2][2][4];
#pragma unroll
  for (int ct = 0; ct < 2; ++ct)
#pragma unroll
    for (int mtl = 0; mtl < 2; ++mtl)
#pragma unroll
      for (int r = 0; r < 4; ++r) { c_[ct][mtl][r] = 0.f; hl[ct][mtl][r] = 0.f; }
  if (t_begin != 0) {
#pragma unroll
    for (int ct = 0; ct < 2; ++ct)
#pragma unroll
      for (int mtl = 0; mtl < 2; ++mtl)
#pragma unroll
        for (int r = 0; r < 4; ++r) {
          int brow = (w * 2 + mtl) * 16 + ((l >> 4) * 4) + r;
          int col = j0 + ct * 16 + (l & 15);
          c_[ct][mtl][r] = cstate[d * 32768 + brow * 512 + col];
        }
  }

  // register prefetch of xg + mask for a step
  ushort4 xv[4][2][2], xn[4][2][2];
  float   mv[2][4],    mn[2][4];
  auto ld_step = [&](int tt, ushort4 (&xd)[4][2][2], float (&md)[2][4]) {
#pragma unroll
    for (int q = 0; q < 4; ++q)
#pragma unroll
      for (int ct = 0; ct < 2; ++ct)
#pragma unroll
        for (int mtl = 0; mtl < 2; ++mtl) {
          int g = q * 512 + j0 + ct * 16 + (l & 15);
          int m = tt * 64 + (w * 2 + mtl) * 16 + ((l >> 4) * 4);
          xd[q][ct][mtl] = *(const ushort4*)(xgd + (long)g * CM + (m - m_base));
        }
#pragma unroll
    for (int mtl = 0; mtl < 2; ++mtl)
#pragma unroll
      for (int r = 0; r < 4; ++r) {
        int brow = (w * 2 + mtl) * 16 + ((l >> 4) * 4) + r;
        md[mtl][r] = mask[brow * 512 + tt];
      }
  };
  ld_step(d ? (511 - t_begin) : t_begin, xv, mv);

  for (int t = t_begin; t < t_end; ++t) {
    const int tt = d ? (511 - t) : t;

    f32x4 acc[2][2][4] = {};
    if (t > 0) {
      // A[m][k] = h_prev[m][k] from hglob slot t&1; lane: row=l&15, k=(l>>4)*8+j
      const u16* hp = hg + (t & 1) * 32768 + ((l & 15) * 512) + ((l >> 4) * 8);
#pragma unroll
      for (int kk = 0; kk < 16; ++kk) {
        bf16x8 a[4];
#pragma unroll
        for (int mt = 0; mt < 4; ++mt)
          a[mt] = *(const bf16x8*)(hp + mt * 16 * 512 + kk * 32);
#pragma unroll
        for (int g2 = 0; g2 < 2; ++g2)
#pragma unroll
          for (int ct = 0; ct < 2; ++ct)
#pragma unroll
            for (int mt = 0; mt < 4; ++mt)
              acc[g2][ct][mt] = __builtin_amdgcn_mfma_f32_16x16x32_bf16(
                  a[mt], Bf[g2][ct][kk], acc[g2][ct][mt], 0, 0, 0);
      }
    }

    // cross-wave exchange: wave w hands its 2 gate quadrants for the OTHER row-half
    auto do_ex = [&](auto Wc) {
      constexpr int W = decltype(Wc)::value;
#pragma unroll
      for (int g2 = 0; g2 < 2; ++g2)
#pragma unroll
        for (int ct = 0; ct < 2; ++ct)
#pragma unroll
          for (int mtl = 0; mtl < 2; ++mtl)
#pragma unroll
            for (int r = 0; r < 4; ++r)
              ex[W][g2][ct][mtl][r][l] = acc[g2][ct][(W ^ 1) * 2 + mtl][r];
    };
    if (w == 0) do_ex(IC<0>{}); else do_ex(IC<1>{});
    __syncthreads();

    // prefetch NEXT step's xg/mask (immutable data; overlaps pointwise, pre-invalidate)
    if (t + 1 < t_end) ld_step(d ? (511 - (t + 1)) : (t + 1), xn, mn);

    auto do_pw = [&](auto Wc) {
      constexpr int W = decltype(Wc)::value;
#pragma unroll
      for (int ct = 0; ct < 2; ++ct)
#pragma unroll
        for (int mtl = 0; mtl < 2; ++mtl)
#pragma unroll
          for (int r = 0; r < 4; ++r) {
            int brow = (W * 2 + mtl) * 16 + ((l >> 4) * 4) + r;
            float gv[4];
#pragma unroll
            for (int q = 0; q < 4; ++q) {
              float raw = ((q >> 1) == W)
                            ? acc[q & 1][ct][W * 2 + mtl][r]
                            : ex[W ^ 1][q & 1][ct][mtl][r][l];
              gv[q] = raw + bf2f(u4get(xv[q][ct][mtl], r)) + bsum[q][ct];
            }
            float iv = sigf(gv[0]);
            float fv = sigf(gv[1]);
            float gg = tanhf_(gv[2]);
            float ov = sigf(gv[3]);
            float cnew = fv * c_[ct][mtl][r] + iv * gg;
            float hnew = ov * tanhf_(cnew);
            float mvv = mv[mtl][r];
            float h2 = hnew * mvv;
            c_[ct][mtl][r] = cnew * mvv;
            hl[ct][mtl][r] = h2;
            int col = j0 + ct * 16 + (l & 15);
            u16 hb = f2bf(h2);
            hg[(((t + 1) & 1) * 64 + brow) * 512 + col] = hb;
            if (out_mode == 0)
              hs0[((long)brow * 512 + tt) * 1024 + d * 512 + col] = hb;
            else
              outF[((long)brow * 512 + tt) * 1024 + d * 512 + col] = h2;
          }
    };
    if (w == 0) do_pw(IC<0>{}); else do_pw(IC<1>{});

    if (t < t_end - 1) {
      __syncthreads();   // drains all threads' stores to L2 (write-through L1) + exec barrier
      if (tid == 0) {
        // release: publishes this WG's h stores (wbl2) before the count becomes visible
        __hip_atomic_fetch_add(arr, 1, __ATOMIC_RELEASE, __HIP_MEMORY_SCOPE_AGENT);
        const int target = 16 * (t - t_begin + 1);
        while (__hip_atomic_load(arr, __ATOMIC_RELAXED, __HIP_MEMORY_SCOPE_AGENT) < target)
          __builtin_amdgcn_s_sleep(8);
        __builtin_amdgcn_fence(__ATOMIC_ACQUIRE, "agent");  // one inv: fresh h reads
      }
      __syncthreads();
      // shift prefetched step
#pragma unroll
      for (int q = 0; q < 4; ++q)
#pragma unroll
        for (int ct = 0; ct < 2; ++ct)
#pragma unroll
          for (int mtl = 0; mtl < 2; ++mtl) xv[q][ct][mtl] = xn[q][ct][mtl];
#pragma unroll
      for (int mtl = 0; mtl < 2; ++mtl)
#pragma unroll
        for (int r = 0; r < 4; ++r) mv[mtl][r] = mn[mtl][r];
    }
  }

  if (t_end < 512) {
#pragma unroll
    for (int ct = 0; ct < 2; ++ct)
#pragma unroll
      for (int mtl = 0; mtl < 2; ++mtl)
#pragma unroll
        for (int r = 0; r < 4; ++r) {
          int brow = (w * 2 + mtl) * 16 + ((l >> 4) * 4) + r;
          int col = j0 + ct * 16 + (l & 15);
          cstate[d * 32768 + brow * 512 + col] = c_[ct][mtl][r];
        }
  } else {
#pragma unroll
    for (int ct = 0; ct < 2; ++ct)
#pragma unroll
      for (int mtl = 0; mtl < 2; ++mtl)
#pragma unroll
        for (int r = 0; r < 4; ++r) {
          int brow = (w * 2 + mtl) * 16 + ((l >> 4) * 4) + r;
          int col = j0 + ct * 16 + (l & 15);
          hn[brow * 1024 + d * 512 + col] = hl[ct][mtl][r];
          cn[brow * 1024 + d * 512 + col] = c_[ct][mtl][r];
        }
  }
}

extern "C" void kernel_launch(void* const* d_in, const int* in_sizes, int n_in,
                              void* d_out, int out_size, void* d_ws, size_t ws_size,
                              hipStream_t stream) {
  const float* inputs = (const float*)d_in[0];
  const float* mask   = (const float*)d_in[1];
  const float* Wih[2][2] = { { (const float*)d_in[2],  (const float*)d_in[6]  },
                             { (const float*)d_in[10], (const float*)d_in[14] } };
  const float* Whh[2][2] = { { (const float*)d_in[3],  (const float*)d_in[7]  },
                             { (const float*)d_in[11], (const float*)d_in[15] } };
  const float* bih[2][2] = { { (const float*)d_in[4],  (const float*)d_in[8]  },
                             { (const float*)d_in[12], (const float*)d_in[16] } };
  const float* bhh[2][2] = { { (const float*)d_in[5],  (const float*)d_in[9]  },
                             { (const float*)d_in[13], (const float*)d_in[17] } };

  float* outputs = (float*)d_out;            // [64][512][1024] f32
  float* hn      = outputs + 33554432;       // [2][64][1024] f32
  float* cn      = hn + 131072;              // [2][64][1024] f32

  // plan: xg chunk covers TC = 512/nch steps per dir; xg stored bf16
  int nch = 0;
  for (int c : {1, 2, 4, 8, 16, 32}) {
    size_t xg_b = 2048UL * (32768 / c) * 2;
    size_t need = 4096 + 262144 + (c > 1 ? (262144UL + 67108864UL) : 0) + 2 * xg_b;
    if (ws_size >= need) { nch = c; break; }
  }
  if (!nch) {
    hipMemsetAsync(d_out, 0x49, 1024, stream);  // absmax ~8.2e5 marker: ws too small
    return;
  }
  const int TC = 512 / nch;
  const int CM = TC * 64;

  char* ws = (char*)d_ws;
  int*   arrive = (int*)ws;                          // 16 B used
  u16*   hglob  = (u16*)(ws + 4096);                 // [2][2][64][512] bf16
  float* cstate = (float*)(ws + 4096 + 262144);      // [2][64][512] f32 (nch>1)
  u16*   hs0;
  u16*   xg_fw;
  if (nch > 1) {
    hs0   = (u16*)(ws + 4096 + 262144 + 262144);
    xg_fw = (u16*)(ws + 4096 + 262144 + 262144 + 67108864);
  } else {
    hs0   = (u16*)d_out;   // bf16 hs0 aliased into outputs region (safe: GEMM precedes rec)
    xg_fw = (u16*)(ws + 4096 + 262144);
  }
  u16* xg_bw = xg_fw + 2048L * CM;

  for (int layer = 0; layer < 2; ++layer) {
    for (int cc = 0; cc < nch; ++cc) {
      const int mb_fw = cc * CM;
      const int mb_bw = 32768 - (cc + 1) * CM;
      dim3 g(16, CM / 128, 2);
      if (layer == 0)
        xg_gemm<512, 1><<<g, 256, 0, stream>>>(inputs, Wih[0][0], Wih[0][1],
                                               xg_fw, xg_bw, mb_fw, mb_bw, CM);
      else
        xg_gemm<1024, 0><<<g, 256, 0, stream>>>(hs0, Wih[1][0], Wih[1][1],
                                                xg_fw, xg_bw, mb_fw, mb_bw, CM);
      hipMemsetAsync(arrive, 0, 16, stream);
      lstm_rec<<<32, 128, 0, stream>>>(
          xg_fw, xg_bw, mb_fw, mb_bw, CM,
          Whh[layer][0], Whh[layer][1],
          bih[layer][0], bhh[layer][0], bih[layer][1], bhh[layer][1],
          mask, hs0, outputs, layer,
          hn + layer * 65536, cn + layer * 65536,
          cstate, hglob, cc * TC, (cc + 1) * TC, arrive);
    }
  }
}

// Round 5
// 28627.670 us; speedup vs baseline: 1.0465x; 1.0465x over previous
//
#include <hip/hip_runtime.h>
#include <stdint.h>

// 2-layer bidirectional LSTM, B=64 S=512 IN=512 H=512. I/O f32; MFMA operands bf16;
// gate math f32. Gate order i,f,g,o.
//
//  xg[d][g][m] = x[m] @ Wih_d^T  (MFMA GEMM, fused fw+bw via blockIdx.z), m = tt*64+b.
//  recurrence: 32 WGs (16/dir, 32 h-cols each, 2 waves); Whh slice register-resident.
//  h exchange: per-access coherent (sc0 sc1) stores/loads on a 2-slot ring — NO fences.
//  barrier: relaxed fetch_add arrivals + last-arriver publishes `go` flag on a separate
//  cache line; others poll `go` with plain relaxed loads (no RMW contention).
//  h loads: 4-deep software pipeline of global_load_dwordx4 sc0 sc1 with counted
//  s_waitcnt vmcnt(12) + sched_barrier (uniform via dummy tail issues).
//
//  ws: [sync 4096B: arr/go per dir on separate lines][hglob 2*2*64*512*2B]
//      [cstate 2*64*512*4B (nch>1)][hs0 67MB (nch>1; else aliased into d_out)][xg_fw][xg_bw]

typedef short bf16x8 __attribute__((ext_vector_type(8)));
typedef float f32x4 __attribute__((ext_vector_type(4)));
typedef unsigned short u16;

template<int N> struct IC { static constexpr int value = N; };

__device__ __forceinline__ float bf2f(u16 u) {
  union { uint32_t i; float f; } v; v.i = ((uint32_t)u) << 16; return v.f;
}
__device__ __forceinline__ u16 f2bf(float f) {
  union { float f; uint32_t i; } v; v.f = f;
  uint32_t u = v.i;
  return (u16)((u + 0x7FFFu + ((u >> 16) & 1u)) >> 16);
}
__device__ __forceinline__ float sigf(float x) { return 1.0f / (1.0f + __expf(-x)); }
__device__ __forceinline__ float tanhf_(float x) { return 2.0f / (1.0f + __expf(-2.0f * x)) - 1.0f; }
__device__ __forceinline__ u16 u4get(ushort4 v, int r) {
  return r == 0 ? v.x : r == 1 ? v.y : r == 2 ? v.z : v.w;
}
__device__ __forceinline__ bf16x8 ld8f32(const float* p) {
  float4 a = *(const float4*)p;
  float4 b = *(const float4*)(p + 4);
  bf16x8 r;
  r[0] = (short)f2bf(a.x); r[1] = (short)f2bf(a.y);
  r[2] = (short)f2bf(a.z); r[3] = (short)f2bf(a.w);
  r[4] = (short)f2bf(b.x); r[5] = (short)f2bf(b.y);
  r[6] = (short)f2bf(b.z); r[7] = (short)f2bf(b.w);
  return r;
}

// coherent (cross-XCD, bypass L1/L2) 16B load / 2B store
__device__ __forceinline__ void ldg_sc(bf16x8& d, const u16* p) {
  asm volatile("global_load_dwordx4 %0, %1, off sc0 sc1" : "=&v"(d) : "v"(p));
}
__device__ __forceinline__ void stg_sc16(u16* p, u16 v) {
  uint32_t vv = v;
  asm volatile("global_store_short %0, %1, off sc0 sc1" :: "v"(p), "v"(vv) : "memory");
}
template<int N>
__device__ __forceinline__ void s_wait_vmcnt() {
  asm volatile("s_waitcnt vmcnt(%0)" :: "n"(N) : "memory");
  __builtin_amdgcn_sched_barrier(0);
}

// ---------------- xg GEMM: xg[n][m-m_base] = sum_k A[m][k] * W[n][k] ----------------
// A[m][k] = Abuf[((m&63)*512 + (m>>6))*KDIM + k]; AF32=1: f32 (inputs), 0: bf16 (hs0).
// blockIdx.z selects direction. grid (16, CM/128, 2), block 256.
template<int KDIM, int AF32>
__global__ __launch_bounds__(256) void xg_gemm(
    const void* __restrict__ Av,
    const float* __restrict__ Wfw, const float* __restrict__ Wbw,
    u16* __restrict__ xgf, u16* __restrict__ xgb,
    int mb_fw, int mb_bw, int CM)
{
  const int tid = threadIdx.x;
  const int l = tid & 63, w = tid >> 6;
  const int wm = w & 1, wn = w >> 1;
  const int z = blockIdx.z;
  const float* W = z ? Wbw : Wfw;
  u16* xg = z ? xgb : xgf;
  const int m_base = z ? mb_bw : mb_fw;
  const int m0 = m_base + blockIdx.y * 128 + wm * 64;
  const int n0 = blockIdx.x * 128 + wn * 64;

  const float* Af = (const float*)Av;
  const u16*   Au = (const u16*)Av;
  long aoff[4];
#pragma unroll
  for (int mt = 0; mt < 4; ++mt) {
    int m = m0 + mt * 16 + (l & 15);
    aoff[mt] = ((long)(m & 63) * 512 + (m >> 6)) * KDIM + ((l >> 4) * 8);
  }
  const float* brow[4];
#pragma unroll
  for (int nt = 0; nt < 4; ++nt) {
    int n = n0 + nt * 16 + (l & 15);
    brow[nt] = W + (long)n * KDIM + ((l >> 4) * 8);
  }
  f32x4 acc[4][4] = {};
  for (int kk = 0; kk < KDIM / 32; ++kk) {
    bf16x8 a[4], b[4];
#pragma unroll
    for (int mt = 0; mt < 4; ++mt) {
      if constexpr (AF32) a[mt] = ld8f32(Af + aoff[mt] + kk * 32);
      else                a[mt] = *(const bf16x8*)(Au + aoff[mt] + kk * 32);
    }
#pragma unroll
    for (int nt = 0; nt < 4; ++nt) b[nt] = ld8f32(brow[nt] + kk * 32);
#pragma unroll
    for (int mt = 0; mt < 4; ++mt)
#pragma unroll
      for (int nt = 0; nt < 4; ++nt)
        acc[mt][nt] = __builtin_amdgcn_mfma_f32_16x16x32_bf16(a[mt], b[nt], acc[mt][nt], 0, 0, 0);
  }
#pragma unroll
  for (int nt = 0; nt < 4; ++nt) {
    int n = n0 + nt * 16 + (l & 15);
    long cb = (long)n * CM;
#pragma unroll
    for (int mt = 0; mt < 4; ++mt) {
      int mr = (m0 - m_base) + mt * 16 + (l >> 4) * 4;
      ushort4 u;
      u.x = f2bf(acc[mt][nt][0]); u.y = f2bf(acc[mt][nt][1]);
      u.z = f2bf(acc[mt][nt][2]); u.w = f2bf(acc[mt][nt][3]);
      *(ushort4*)(xg + cb + mr) = u;
    }
  }
}

// ---------------- recurrence ----------------
// grid=32: d=blockIdx.x>>4, wg=blockIdx.x&15 (h-cols [wg*32,wg*32+32)). 2 waves/block.
__global__ __launch_bounds__(128, 1) void lstm_rec(
    const u16* __restrict__ xg_fw, const u16* __restrict__ xg_bw,
    int mb_fw, int mb_bw, int CM,
    const float* __restrict__ Whh_fw, const float* __restrict__ Whh_bw,
    const float* __restrict__ bih_fw, const float* __restrict__ bhh_fw,
    const float* __restrict__ bih_bw, const float* __restrict__ bhh_bw,
    const float* __restrict__ mask,
    u16* __restrict__ hs0, float* __restrict__ outF, int out_mode,
    float* __restrict__ hn, float* __restrict__ cn,
    float* __restrict__ cstate, u16* __restrict__ hglob,
    int t_begin, int t_end, int* __restrict__ sync)
{
  const int tid = threadIdx.x;
  const int l = tid & 63;
  const int w = tid >> 6;
  const int d = blockIdx.x >> 4;
  const int wg = blockIdx.x & 15;
  const int j0 = wg * 32;

  const float* Whh = d ? Whh_bw : Whh_fw;
  const float* bih = d ? bih_bw : bih_fw;
  const float* bhh = d ? bhh_bw : bhh_fw;
  const u16* xgd = d ? xg_bw : xg_fw;
  const int m_base = d ? mb_bw : mb_fw;
  u16* hg = hglob + d * 2 * 32768;          // [2 slots][64][512]
  int* arr = sync + d * 64;                 // arrive counter (own line)
  int* go  = sync + d * 64 + 32;            // go flag (separate line)

  __shared__ float ex[2][2][2][2][4][64];   // [srcwave][g2][ct][mtl][r][lane] = 16KB

  // Whh fragments (bf16): B-op[k][n]=Whh[n][k]; lane: col=l&15, k=(l>>4)*8+j
  bf16x8 Bf[2][2][16];
#pragma unroll
  for (int g2 = 0; g2 < 2; ++g2) {
#pragma unroll
    for (int ct = 0; ct < 2; ++ct) {
      const int grow = (w * 2 + g2) * 512 + j0 + ct * 16 + (l & 15);
      const float* p = Whh + (long)grow * 512 + ((l >> 4) * 8);
#pragma unroll
      for (int kk = 0; kk < 16; ++kk)
        Bf[g2][ct][kk] = ld8f32(p + kk * 32);
    }
  }
  float bsum[4][2];
#pragma unroll
  for (int q = 0; q < 4; ++q)
#pragma unroll
    for (int ct = 0; ct < 2; ++ct) {
      int g = q * 512 + j0 + ct * 16 + (l & 15);
      bsum[q][ct] = bih[g] + bhh[g];
    }

  float c_[2][2][4];
  float hl[2][2][4];
#pragma unroll
  for (int ct = 0; ct < 2; ++ct)
#pragma unroll
    for (int mtl = 0; mtl < 2; ++mtl)
#pragma unroll
      for (int r = 0; r < 4; ++r) { c_[ct][mtl][r] = 0.f; hl[ct][mtl][r] = 0.f; }
  if (t_begin != 0) {
#pragma unroll
    for (int ct = 0; ct < 2; ++ct)
#pragma unroll
      for (int mtl = 0; mtl < 2; ++mtl)
#pragma unroll
        for (int r = 0; r < 4; ++r) {
          int brow = (w * 2 + mtl) * 16 + ((l >> 4) * 4) + r;
          int col = j0 + ct * 16 + (l & 15);
          c_[ct][mtl][r] = cstate[d * 32768 + brow * 512 + col];
        }
  }

  // register prefetch of xg + mask for a step (immutable -> normal cached loads)
  ushort4 xv[4][2][2], xn[4][2][2];
  float   mv[2][4],    mn[2][4];
  auto ld_step = [&](int tt, ushort4 (&xd)[4][2][2], float (&md)[2][4]) {
#pragma unroll
    for (int q = 0; q < 4; ++q)
#pragma unroll
      for (int ct = 0; ct < 2; ++ct)
#pragma unroll
        for (int mtl = 0; mtl < 2; ++mtl) {
          int g = q * 512 + j0 + ct * 16 + (l & 15);
          int m = tt * 64 + (w * 2 + mtl) * 16 + ((l >> 4) * 4);
          xd[q][ct][mtl] = *(const ushort4*)(xgd + (long)g * CM + (m - m_base));
        }
#pragma unroll
    for (int mtl = 0; mtl < 2; ++mtl)
#pragma unroll
      for (int r = 0; r < 4; ++r) {
        int brow = (w * 2 + mtl) * 16 + ((l >> 4) * 4) + r;
        md[mtl][r] = mask[brow * 512 + tt];
      }
  };
  ld_step(d ? (511 - t_begin) : t_begin, xv, mv);

  for (int t = t_begin; t < t_end; ++t) {
    const int tt = d ? (511 - t) : t;

    f32x4 acc[2][2][4] = {};
    if (t > 0) {
      // A[m][k] = h_prev[m][k] from hg slot t&1; lane: row=l&15, k=(l>>4)*8+j.
      // Coherent sc0sc1 loads, 4-deep pipeline, counted vmcnt(12).
      const u16* hp = hg + (t & 1) * 32768 + ((l & 15) * 512) + ((l >> 4) * 8);
      bf16x8 ha[4][4];
#pragma unroll
      for (int g = 0; g < 3; ++g)
#pragma unroll
        for (int mt = 0; mt < 4; ++mt)
          ldg_sc(ha[g][mt], hp + mt * 16 * 512 + g * 32);
#pragma unroll
      for (int kk = 0; kk < 16; ++kk) {
        const int gi = (kk + 3) & 15;   // address group (wraps to dummy re-reads at tail)
        const int gb = (kk + 3) & 3;    // buffer slot
#pragma unroll
        for (int mt = 0; mt < 4; ++mt)
          ldg_sc(ha[gb][mt], hp + mt * 16 * 512 + gi * 32);
        s_wait_vmcnt<12>();             // group kk complete (in-order retirement)
#pragma unroll
        for (int g2 = 0; g2 < 2; ++g2)
#pragma unroll
          for (int ct = 0; ct < 2; ++ct)
#pragma unroll
            for (int mt = 0; mt < 4; ++mt)
              acc[g2][ct][mt] = __builtin_amdgcn_mfma_f32_16x16x32_bf16(
                  ha[kk & 3][mt], Bf[g2][ct][kk], acc[g2][ct][mt], 0, 0, 0);
      }
    }

    // cross-wave exchange: wave w hands its 2 gate quadrants for the OTHER row-half
    auto do_ex = [&](auto Wc) {
      constexpr int W = decltype(Wc)::value;
#pragma unroll
      for (int g2 = 0; g2 < 2; ++g2)
#pragma unroll
        for (int ct = 0; ct < 2; ++ct)
#pragma unroll
          for (int mtl = 0; mtl < 2; ++mtl)
#pragma unroll
            for (int r = 0; r < 4; ++r)
              ex[W][g2][ct][mtl][r][l] = acc[g2][ct][(W ^ 1) * 2 + mtl][r];
    };
    if (w == 0) do_ex(IC<0>{}); else do_ex(IC<1>{});
    __syncthreads();

    // prefetch NEXT step's xg/mask (immutable; overlaps pointwise + barrier)
    if (t + 1 < t_end) ld_step(d ? (511 - (t + 1)) : (t + 1), xn, mn);

    auto do_pw = [&](auto Wc) {
      constexpr int W = decltype(Wc)::value;
#pragma unroll
      for (int ct = 0; ct < 2; ++ct)
#pragma unroll
        for (int mtl = 0; mtl < 2; ++mtl)
#pragma unroll
          for (int r = 0; r < 4; ++r) {
            int brow = (W * 2 + mtl) * 16 + ((l >> 4) * 4) + r;
            float gv[4];
#pragma unroll
            for (int q = 0; q < 4; ++q) {
              float raw = ((q >> 1) == W)
                            ? acc[q & 1][ct][W * 2 + mtl][r]
                            : ex[W ^ 1][q & 1][ct][mtl][r][l];
              gv[q] = raw + bf2f(u4get(xv[q][ct][mtl], r)) + bsum[q][ct];
            }
            float iv = sigf(gv[0]);
            float fv = sigf(gv[1]);
            float gg = tanhf_(gv[2]);
            float ov = sigf(gv[3]);
            float cnew = fv * c_[ct][mtl][r] + iv * gg;
            float hnew = ov * tanhf_(cnew);
            float mvv = mv[mtl][r];
            float h2 = hnew * mvv;
            c_[ct][mtl][r] = cnew * mvv;
            hl[ct][mtl][r] = h2;
            int col = j0 + ct * 16 + (l & 15);
            u16 hb = f2bf(h2);
            stg_sc16(&hg[(((t + 1) & 1) * 64 + brow) * 512 + col], hb);  // coherent write-through
            if (out_mode == 0)
              hs0[((long)brow * 512 + tt) * 1024 + d * 512 + col] = hb;
            else
              outF[((long)brow * 512 + tt) * 1024 + d * 512 + col] = h2;
          }
    };
    if (w == 0) do_pw(IC<0>{}); else do_pw(IC<1>{});

    if (t < t_end - 1) {
      __syncthreads();   // compiler emits vmcnt(0): all sc-stores acked at coherence point
      if (tid == 0) {
        const int s = t - t_begin + 1;
        int old = __hip_atomic_fetch_add(arr, 1, __ATOMIC_RELAXED, __HIP_MEMORY_SCOPE_AGENT);
        if (old == 16 * s - 1) {
          // last arriver: all h-stores globally visible -> publish go
          __hip_atomic_store(go, s, __ATOMIC_RELAXED, __HIP_MEMORY_SCOPE_AGENT);
        } else {
          while (__hip_atomic_load(go, __ATOMIC_RELAXED, __HIP_MEMORY_SCOPE_AGENT) < s)
            __builtin_amdgcn_s_sleep(2);
        }
      }
      __syncthreads();
      // shift prefetched step
#pragma unroll
      for (int q = 0; q < 4; ++q)
#pragma unroll
        for (int ct = 0; ct < 2; ++ct)
#pragma unroll
          for (int mtl = 0; mtl < 2; ++mtl) xv[q][ct][mtl] = xn[q][ct][mtl];
#pragma unroll
      for (int mtl = 0; mtl < 2; ++mtl)
#pragma unroll
        for (int r = 0; r < 4; ++r) mv[mtl][r] = mn[mtl][r];
    }
  }

  if (t_end < 512) {
#pragma unroll
    for (int ct = 0; ct < 2; ++ct)
#pragma unroll
      for (int mtl = 0; mtl < 2; ++mtl)
#pragma unroll
        for (int r = 0; r < 4; ++r) {
          int brow = (w * 2 + mtl) * 16 + ((l >> 4) * 4) + r;
          int col = j0 + ct * 16 + (l & 15);
          cstate[d * 32768 + brow * 512 + col] = c_[ct][mtl][r];
        }
  } else {
#pragma unroll
    for (int ct = 0; ct < 2; ++ct)
#pragma unroll
      for (int mtl = 0; mtl < 2; ++mtl)
#pragma unroll
        for (int r = 0; r < 4; ++r) {
          int brow = (w * 2 + mtl) * 16 + ((l >> 4) * 4) + r;
          int col = j0 + ct * 16 + (l & 15);
          hn[brow * 1024 + d * 512 + col] = hl[ct][mtl][r];
          cn[brow * 1024 + d * 512 + col] = c_[ct][mtl][r];
        }
  }
}

extern "C" void kernel_launch(void* const* d_in, const int* in_sizes, int n_in,
                              void* d_out, int out_size, void* d_ws, size_t ws_size,
                              hipStream_t stream) {
  const float* inputs = (const float*)d_in[0];
  const float* mask   = (const float*)d_in[1];
  const float* Wih[2][2] = { { (const float*)d_in[2],  (const float*)d_in[6]  },
                             { (const float*)d_in[10], (const float*)d_in[14] } };
  const float* Whh[2][2] = { { (const float*)d_in[3],  (const float*)d_in[7]  },
                             { (const float*)d_in[11], (const float*)d_in[15] } };
  const float* bih[2][2] = { { (const float*)d_in[4],  (const float*)d_in[8]  },
                             { (const float*)d_in[12], (const float*)d_in[16] } };
  const float* bhh[2][2] = { { (const float*)d_in[5],  (const float*)d_in[9]  },
                             { (const float*)d_in[13], (const float*)d_in[17] } };

  float* outputs = (float*)d_out;            // [64][512][1024] f32
  float* hn      = outputs + 33554432;       // [2][64][1024] f32
  float* cn      = hn + 131072;              // [2][64][1024] f32

  // plan: xg chunk covers TC = 512/nch steps per dir; xg stored bf16
  int nch = 0;
  for (int c : {1, 2, 4, 8, 16, 32}) {
    size_t xg_b = 2048UL * (32768 / c) * 2;
    size_t need = 4096 + 262144 + (c > 1 ? (262144UL + 67108864UL) : 0) + 2 * xg_b;
    if (ws_size >= need) { nch = c; break; }
  }
  if (!nch) {
    hipMemsetAsync(d_out, 0x49, 1024, stream);  // absmax ~8.2e5 marker: ws too small
    return;
  }
  const int TC = 512 / nch;
  const int CM = TC * 64;

  char* ws = (char*)d_ws;
  int*   sync   = (int*)ws;                          // arrive/go per dir, separate lines
  u16*   hglob  = (u16*)(ws + 4096);                 // [2][2][64][512] bf16
  float* cstate = (float*)(ws + 4096 + 262144);      // [2][64][512] f32 (nch>1)
  u16*   hs0;
  u16*   xg_fw;
  if (nch > 1) {
    hs0   = (u16*)(ws + 4096 + 262144 + 262144);
    xg_fw = (u16*)(ws + 4096 + 262144 + 262144 + 67108864);
  } else {
    hs0   = (u16*)d_out;   // bf16 hs0 aliased into outputs region (safe: GEMM precedes rec)
    xg_fw = (u16*)(ws + 4096 + 262144);
  }
  u16* xg_bw = xg_fw + 2048L * CM;

  for (int layer = 0; layer < 2; ++layer) {
    for (int cc = 0; cc < nch; ++cc) {
      const int mb_fw = cc * CM;
      const int mb_bw = 32768 - (cc + 1) * CM;
      dim3 g(16, CM / 128, 2);
      if (layer == 0)
        xg_gemm<512, 1><<<g, 256, 0, stream>>>(inputs, Wih[0][0], Wih[0][1],
                                               xg_fw, xg_bw, mb_fw, mb_bw, CM);
      else
        xg_gemm<1024, 0><<<g, 256, 0, stream>>>(hs0, Wih[1][0], Wih[1][1],
                                                xg_fw, xg_bw, mb_fw, mb_bw, CM);
      hipMemsetAsync(sync, 0, 4096, stream);
      lstm_rec<<<32, 128, 0, stream>>>(
          xg_fw, xg_bw, mb_fw, mb_bw, CM,
          Whh[layer][0], Whh[layer][1],
          bih[layer][0], bhh[layer][0], bih[layer][1], bhh[layer][1],
          mask, hs0, outputs, layer,
          hn + layer * 65536, cn + layer * 65536,
          cstate, hglob, cc * TC, (cc + 1) * TC, sync);
    }
  }
}

// Round 7
// 21719.200 us; speedup vs baseline: 1.3793x; 1.3181x over previous
//
#include <hip/hip_runtime.h>
#include <stdint.h>

// 2-layer bidirectional LSTM, B=64 S=512 IN=512 H=512. I/O f32; MFMA operands bf16;
// gate math f32. Gate order i,f,g,o.
//
//  xg block layout: per dir, per (tt, wg) one contiguous 16KB block:
//    [q(4)][ct(2)][w(2)][mtl(2)][mgrp(4)][c16(16)][r(4)]  (bf16 elems)
//  recurrence: 32 WGs (16/dir, 32 h-cols each, 2 waves); Whh slice register-resident.
//  h exchange: coherent (sc0 sc1) stores to a 2-slot global ring; each step the WG
//  cooperatively stages the 64KB h matrix into LDS (XOR-swizzled rows) with 2 batches
//  of MLP-16 coherent dwordx4 loads; MFMA A-frags via ds_read_b128 (2-way = free).
//  barrier: relaxed fetch_add arrivals + last-arriver publishes go (separate line);
//  pollers use plain relaxed loads.
//
//  ws: [sync 4096B][hglob 2*2*64*512*2B][cstate (nch>1)][hs0 (nch>1)][xg_fw][xg_bw]

typedef short bf16x8 __attribute__((ext_vector_type(8)));
typedef float f32x4 __attribute__((ext_vector_type(4)));
typedef unsigned short u16;

template<int N> struct IC { static constexpr int value = N; };

__device__ __forceinline__ float bf2f(u16 u) {
  union { uint32_t i; float f; } v; v.i = ((uint32_t)u) << 16; return v.f;
}
__device__ __forceinline__ u16 f2bf(float f) {
  union { float f; uint32_t i; } v; v.f = f;
  uint32_t u = v.i;
  return (u16)((u + 0x7FFFu + ((u >> 16) & 1u)) >> 16);
}
__device__ __forceinline__ float sigf(float x) { return 1.0f / (1.0f + __expf(-x)); }
__device__ __forceinline__ float tanhf_(float x) { return 2.0f / (1.0f + __expf(-2.0f * x)) - 1.0f; }
__device__ __forceinline__ u16 u4get(ushort4 v, int r) {
  return r == 0 ? v.x : r == 1 ? v.y : r == 2 ? v.z : v.w;
}
__device__ __forceinline__ bf16x8 ld8f32(const float* p) {
  float4 a = *(const float4*)p;
  float4 b = *(const float4*)(p + 4);
  bf16x8 r;
  r[0] = (short)f2bf(a.x); r[1] = (short)f2bf(a.y);
  r[2] = (short)f2bf(a.z); r[3] = (short)f2bf(a.w);
  r[4] = (short)f2bf(b.x); r[5] = (short)f2bf(b.y);
  r[6] = (short)f2bf(b.z); r[7] = (short)f2bf(b.w);
  return r;
}
// coherent (cross-XCD) 16B load / 2B store
__device__ __forceinline__ void ldg_sc(bf16x8& d, const u16* p) {
  asm volatile("global_load_dwordx4 %0, %1, off sc0 sc1" : "=&v"(d) : "v"(p));
}
__device__ __forceinline__ void stg_sc16(u16* p, u16 v) {
  uint32_t vv = v;
  asm volatile("global_store_short %0, %1, off sc0 sc1" :: "v"(p), "v"(vv) : "memory");
}
__device__ __forceinline__ void wait_vm0() {
  asm volatile("s_waitcnt vmcnt(0)" ::: "memory");
  __builtin_amdgcn_sched_barrier(0);
}

// ---------------- xg GEMM ----------------
// A[m][k] = Abuf[((m&63)*512 + (m>>6))*KDIM + k]; AF32=1: f32 (inputs), 0: bf16 (hs0).
// Output: per-(tt,wg) 16KB blocks. grid (16, CM/128, 2), block 256.
template<int KDIM, int AF32>
__global__ __launch_bounds__(256) void xg_gemm(
    const void* __restrict__ Av,
    const float* __restrict__ Wfw, const float* __restrict__ Wbw,
    u16* __restrict__ xgf, u16* __restrict__ xgb,
    int mb_fw, int mb_bw)
{
  const int tid = threadIdx.x;
  const int l = tid & 63, w = tid >> 6;
  const int wm = w & 1, wn = w >> 1;
  const int z = blockIdx.z;
  const float* W = z ? Wbw : Wfw;
  u16* xg = z ? xgb : xgf;
  const int m_base = z ? mb_bw : mb_fw;
  const int m0 = m_base + blockIdx.y * 128 + wm * 64;
  const int n0 = blockIdx.x * 128 + wn * 64;

  const float* Af = (const float*)Av;
  const u16*   Au = (const u16*)Av;
  long aoff[4];
#pragma unroll
  for (int mt = 0; mt < 4; ++mt) {
    int m = m0 + mt * 16 + (l & 15);
    aoff[mt] = ((long)(m & 63) * 512 + (m >> 6)) * KDIM + ((l >> 4) * 8);
  }
  const float* brow[4];
#pragma unroll
  for (int nt = 0; nt < 4; ++nt) {
    int n = n0 + nt * 16 + (l & 15);
    brow[nt] = W + (long)n * KDIM + ((l >> 4) * 8);
  }
  f32x4 acc[4][4] = {};
  for (int kk = 0; kk < KDIM / 32; ++kk) {
    bf16x8 a[4], b[4];
#pragma unroll
    for (int mt = 0; mt < 4; ++mt) {
      if constexpr (AF32) a[mt] = ld8f32(Af + aoff[mt] + kk * 32);
      else                a[mt] = *(const bf16x8*)(Au + aoff[mt] + kk * 32);
    }
#pragma unroll
    for (int nt = 0; nt < 4; ++nt) b[nt] = ld8f32(brow[nt] + kk * 32);
#pragma unroll
    for (int mt = 0; mt < 4; ++mt)
#pragma unroll
      for (int nt = 0; nt < 4; ++nt)
        acc[mt][nt] = __builtin_amdgcn_mfma_f32_16x16x32_bf16(a[mt], b[nt], acc[mt][nt], 0, 0, 0);
  }
  // store into block layout; D frag: n = n0+nt*16+(l&15), m = m0+mt*16+(l>>4)*4+r
  const int ttg = (m0 - m_base) >> 6;   // chunk-relative tt
#pragma unroll
  for (int nt = 0; nt < 4; ++nt) {
    const int nu = n0 + nt * 16;        // lane-uniform part of n
    const int q  = nu >> 9;
    const int wgi = (nu >> 5) & 15;
    const int ct  = (nu >> 4) & 1;
#pragma unroll
    for (int mt = 0; mt < 4; ++mt) {
      long boff = ((long)ttg * 16 + wgi) * 8192
                + q * 2048 + ct * 1024 + (mt >> 1) * 512 + (mt & 1) * 256
                + (l >> 4) * 64 + (l & 15) * 4;
      ushort4 u;
      u.x = f2bf(acc[mt][nt][0]); u.y = f2bf(acc[mt][nt][1]);
      u.z = f2bf(acc[mt][nt][2]); u.w = f2bf(acc[mt][nt][3]);
      *(ushort4*)(xg + boff) = u;
    }
  }
}

// ---------------- recurrence ----------------
// grid=32: d=blockIdx.x>>4, wg=blockIdx.x&15 (h-cols [wg*32,wg*32+32)). 2 waves/block.
__global__ __launch_bounds__(128, 1) void lstm_rec(
    const u16* __restrict__ xg_fw, const u16* __restrict__ xg_bw,
    int t0_fw, int t0_bw,
    const float* __restrict__ Whh_fw, const float* __restrict__ Whh_bw,
    const float* __restrict__ bih_fw, const float* __restrict__ bhh_fw,
    const float* __restrict__ bih_bw, const float* __restrict__ bhh_bw,
    const float* __restrict__ mask,
    u16* __restrict__ hs0, float* __restrict__ outF, int out_mode,
    float* __restrict__ hn, float* __restrict__ cn,
    float* __restrict__ cstate, u16* __restrict__ hglob,
    int t_begin, int t_end, int* __restrict__ sync)
{
  const int tid = threadIdx.x;
  const int l = tid & 63;
  const int w = tid >> 6;
  const int d = blockIdx.x >> 4;
  const int wg = blockIdx.x & 15;
  const int j0 = wg * 32;

  const float* Whh = d ? Whh_bw : Whh_fw;
  const float* bih = d ? bih_bw : bih_fw;
  const float* bhh = d ? bhh_bw : bhh_fw;
  const u16* xgd = d ? xg_bw : xg_fw;
  const int t0 = d ? t0_bw : t0_fw;
  u16* hg = hglob + d * 2 * 32768;          // [2 slots][64][512]
  int* arr = sync + d * 64;                 // arrive counter (own line)
  int* go  = sync + d * 64 + 32;            // go flag (separate line)

  __shared__ float ex[2][2][2][2][4][64];   // exchange, 16KB
  __shared__ u16 hlds[32768];               // staged h, 64KB, XOR-swizzled rows

  // Whh fragments (bf16): B-op[k][n]=Whh[n][k]; lane: col=l&15, k=(l>>4)*8+j
  bf16x8 Bf[2][2][16];
#pragma unroll
  for (int g2 = 0; g2 < 2; ++g2) {
#pragma unroll
    for (int ct = 0; ct < 2; ++ct) {
      const int grow = (w * 2 + g2) * 512 + j0 + ct * 16 + (l & 15);
      const float* p = Whh + (long)grow * 512 + ((l >> 4) * 8);
#pragma unroll
      for (int kk = 0; kk < 16; ++kk)
        Bf[g2][ct][kk] = ld8f32(p + kk * 32);
    }
  }
  float bsum[4][2];
#pragma unroll
  for (int q = 0; q < 4; ++q)
#pragma unroll
    for (int ct = 0; ct < 2; ++ct) {
      int g = q * 512 + j0 + ct * 16 + (l & 15);
      bsum[q][ct] = bih[g] + bhh[g];
    }

  float c_[2][2][4];
  float hl[2][2][4];
#pragma unroll
  for (int ct = 0; ct < 2; ++ct)
#pragma unroll
    for (int mtl = 0; mtl < 2; ++mtl)
#pragma unroll
      for (int r = 0; r < 4; ++r) { c_[ct][mtl][r] = 0.f; hl[ct][mtl][r] = 0.f; }
  if (t_begin != 0) {
#pragma unroll
    for (int ct = 0; ct < 2; ++ct)
#pragma unroll
      for (int mtl = 0; mtl < 2; ++mtl)
#pragma unroll
        for (int r = 0; r < 4; ++r) {
          int brow = (w * 2 + mtl) * 16 + ((l >> 4) * 4) + r;
          int col = j0 + ct * 16 + (l & 15);
          c_[ct][mtl][r] = cstate[d * 32768 + brow * 512 + col];
        }
  }

  // xg + mask register prefetch; per-WG per-step block is contiguous 16KB
  ushort4 xv[4][2][2] = {}, xn[4][2][2] = {};
  float   mv[2][4] = {},    mn[2][4] = {};
  const int lo_off = (l >> 4) * 64 + (l & 15) * 4;
  auto ld_step = [&](int tt, ushort4 (&xd)[4][2][2], float (&md)[2][4]) {
    const u16* bp = xgd + ((long)(tt - t0) * 16 + wg) * 8192 + lo_off;
#pragma unroll
    for (int q = 0; q < 4; ++q)
#pragma unroll
      for (int ct = 0; ct < 2; ++ct)
#pragma unroll
        for (int mtl = 0; mtl < 2; ++mtl)
          xd[q][ct][mtl] = *(const ushort4*)(bp + q * 2048 + ct * 1024 + w * 512 + mtl * 256);
#pragma unroll
    for (int mtl = 0; mtl < 2; ++mtl)
#pragma unroll
      for (int r = 0; r < 4; ++r) {
        int brow = (w * 2 + mtl) * 16 + ((l >> 4) * 4) + r;
        md[mtl][r] = mask[brow * 512 + tt];
      }
  };
  ld_step(d ? (511 - t_begin) : t_begin, xv, mv);

  for (int t = t_begin; t < t_end; ++t) {
    const int tt = d ? (511 - t) : t;

    // ---- cooperative h stage: 64KB global (coherent) -> LDS, 2 batches of 16 ----
    if (t > 0) {
      const u16* hsrc = hg + (t & 1) * 32768;
#pragma unroll
      for (int bt = 0; bt < 2; ++bt) {
        bf16x8 tmp[16];
#pragma unroll
        for (int i = 0; i < 16; ++i) {
          int c = (bt * 16 + i) * 128 + tid;     // chunk 0..4095 (16B each)
          ldg_sc(tmp[i], hsrc + c * 8);
        }
        wait_vm0();
#pragma unroll
        for (int i = 0; i < 16; ++i) {
          int c = (bt * 16 + i) * 128 + tid;
          int row = c >> 6;                       // byte>>10
          int kb = (c & 63) * 16;                 // byte within row
          *(bf16x8*)((char*)hlds + row * 1024 + (kb ^ ((row & 7) << 4))) = tmp[i];
        }
      }
    }
    __syncthreads();

    f32x4 acc[2][2][4] = {};
    if (t > 0) {
#pragma unroll
      for (int kk = 0; kk < 16; ++kk) {
        bf16x8 a[4];
#pragma unroll
        for (int mt = 0; mt < 4; ++mt) {
          int r = (l & 15) + mt * 16;
          int kb = kk * 64 + (l >> 4) * 16;
          a[mt] = *(const bf16x8*)((const char*)hlds + r * 1024 + (kb ^ ((r & 7) << 4)));
        }
#pragma unroll
        for (int g2 = 0; g2 < 2; ++g2)
#pragma unroll
          for (int ct = 0; ct < 2; ++ct)
#pragma unroll
            for (int mt = 0; mt < 4; ++mt)
              acc[g2][ct][mt] = __builtin_amdgcn_mfma_f32_16x16x32_bf16(
                  a[mt], Bf[g2][ct][kk], acc[g2][ct][mt], 0, 0, 0);
      }
    }

    // cross-wave exchange: wave w hands its 2 gate quadrants for the OTHER row-half
    auto do_ex = [&](auto Wc) {
      constexpr int W = decltype(Wc)::value;
#pragma unroll
      for (int g2 = 0; g2 < 2; ++g2)
#pragma unroll
        for (int ct = 0; ct < 2; ++ct)
#pragma unroll
          for (int mtl = 0; mtl < 2; ++mtl)
#pragma unroll
            for (int r = 0; r < 4; ++r)
              ex[W][g2][ct][mtl][r][l] = acc[g2][ct][(W ^ 1) * 2 + mtl][r];
    };
    if (w == 0) do_ex(IC<0>{}); else do_ex(IC<1>{});
    __syncthreads();

    // prefetch NEXT step's xg/mask (immutable; overlaps pointwise + barrier)
    if (t + 1 < t_end) ld_step(d ? (511 - (t + 1)) : (t + 1), xn, mn);

    auto do_pw = [&](auto Wc) {
      constexpr int W = decltype(Wc)::value;
#pragma unroll
      for (int ct = 0; ct < 2; ++ct)
#pragma unroll
        for (int mtl = 0; mtl < 2; ++mtl)
#pragma unroll
          for (int r = 0; r < 4; ++r) {
            int brow = (W * 2 + mtl) * 16 + ((l >> 4) * 4) + r;
            float gv[4];
#pragma unroll
            for (int q = 0; q < 4; ++q) {
              float raw = ((q >> 1) == W)
                            ? acc[q & 1][ct][W * 2 + mtl][r]
                            : ex[W ^ 1][q & 1][ct][mtl][r][l];
              gv[q] = raw + bf2f(u4get(xv[q][ct][mtl], r)) + bsum[q][ct];
            }
            float iv = sigf(gv[0]);
            float fv = sigf(gv[1]);
            float gg = tanhf_(gv[2]);
            float ov = sigf(gv[3]);
            float cnew = fv * c_[ct][mtl][r] + iv * gg;
            float hnew = ov * tanhf_(cnew);
            float mvv = mv[mtl][r];
            float h2 = hnew * mvv;
            c_[ct][mtl][r] = cnew * mvv;
            hl[ct][mtl][r] = h2;
            int col = j0 + ct * 16 + (l & 15);
            u16 hb = f2bf(h2);
            stg_sc16(&hg[(((t + 1) & 1) * 64 + brow) * 512 + col], hb);
            if (out_mode == 0)
              hs0[((long)brow * 512 + tt) * 1024 + d * 512 + col] = hb;
            else
              outF[((long)brow * 512 + tt) * 1024 + d * 512 + col] = h2;
          }
    };
    if (w == 0) do_pw(IC<0>{}); else do_pw(IC<1>{});

    if (t < t_end - 1) {
      __syncthreads();   // drains stores (vmcnt 0) before arrival
      if (tid == 0) {
        const int s = t - t_begin + 1;
        int old = __hip_atomic_fetch_add(arr, 1, __ATOMIC_RELAXED, __HIP_MEMORY_SCOPE_AGENT);
        if (old == 16 * s - 1) {
          __hip_atomic_store(go, s, __ATOMIC_RELAXED, __HIP_MEMORY_SCOPE_AGENT);
        } else {
          while (__hip_atomic_load(go, __ATOMIC_RELAXED, __HIP_MEMORY_SCOPE_AGENT) < s)
            __builtin_amdgcn_s_sleep(2);
        }
      }
      __syncthreads();
#pragma unroll
      for (int q = 0; q < 4; ++q)
#pragma unroll
        for (int ct = 0; ct < 2; ++ct)
#pragma unroll
          for (int mtl = 0; mtl < 2; ++mtl) xv[q][ct][mtl] = xn[q][ct][mtl];
#pragma unroll
      for (int mtl = 0; mtl < 2; ++mtl)
#pragma unroll
        for (int r = 0; r < 4; ++r) mv[mtl][r] = mn[mtl][r];
    }
  }

  if (t_end < 512) {
#pragma unroll
    for (int ct = 0; ct < 2; ++ct)
#pragma unroll
      for (int mtl = 0; mtl < 2; ++mtl)
#pragma unroll
        for (int r = 0; r < 4; ++r) {
          int brow = (w * 2 + mtl) * 16 + ((l >> 4) * 4) + r;
          int col = j0 + ct * 16 + (l & 15);
          cstate[d * 32768 + brow * 512 + col] = c_[ct][mtl][r];
        }
  } else {
#pragma unroll
    for (int ct = 0; ct < 2; ++ct)
#pragma unroll
      for (int mtl = 0; mtl < 2; ++mtl)
#pragma unroll
        for (int r = 0; r < 4; ++r) {
          int brow = (w * 2 + mtl) * 16 + ((l >> 4) * 4) + r;
          int col = j0 + ct * 16 + (l & 15);
          hn[brow * 1024 + d * 512 + col] = hl[ct][mtl][r];
          cn[brow * 1024 + d * 512 + col] = c_[ct][mtl][r];
        }
  }
}

extern "C" void kernel_launch(void* const* d_in, const int* in_sizes, int n_in,
                              void* d_out, int out_size, void* d_ws, size_t ws_size,
                              hipStream_t stream) {
  const float* inputs = (const float*)d_in[0];
  const float* mask   = (const float*)d_in[1];
  const float* Wih[2][2] = { { (const float*)d_in[2],  (const float*)d_in[6]  },
                             { (const float*)d_in[10], (const float*)d_in[14] } };
  const float* Whh[2][2] = { { (const float*)d_in[3],  (const float*)d_in[7]  },
                             { (const float*)d_in[11], (const float*)d_in[15] } };
  const float* bih[2][2] = { { (const float*)d_in[4],  (const float*)d_in[8]  },
                             { (const float*)d_in[12], (const float*)d_in[16] } };
  const float* bhh[2][2] = { { (const float*)d_in[5],  (const float*)d_in[9]  },
                             { (const float*)d_in[13], (const float*)d_in[17] } };

  float* outputs = (float*)d_out;            // [64][512][1024] f32
  float* hn      = outputs + 33554432;       // [2][64][1024] f32
  float* cn      = hn + 131072;              // [2][64][1024] f32

  int nch = 0;
  for (int c : {1, 2, 4, 8, 16, 32}) {
    size_t xg_b = 2048UL * (32768 / c) * 2;   // per-dir chunk bytes
    size_t need = 4096 + 262144 + (c > 1 ? (262144UL + 67108864UL) : 0) + 2 * xg_b;
    if (ws_size >= need) { nch = c; break; }
  }
  if (!nch) {
    hipMemsetAsync(d_out, 0x49, 1024, stream);
    return;
  }
  const int TC = 512 / nch;
  const int CM = TC * 64;

  char* ws = (char*)d_ws;
  int*   sync   = (int*)ws;
  u16*   hglob  = (u16*)(ws + 4096);
  float* cstate = (float*)(ws + 4096 + 262144);
  u16*   hs0;
  u16*   xg_fw;
  if (nch > 1) {
    hs0   = (u16*)(ws + 4096 + 262144 + 262144);
    xg_fw = (u16*)(ws + 4096 + 262144 + 262144 + 67108864);
  } else {
    hs0   = (u16*)d_out;   // bf16 hs0 aliased into outputs region (GEMM precedes rec)
    xg_fw = (u16*)(ws + 4096 + 262144);
  }
  u16* xg_bw = xg_fw + 2048L * CM;

  for (int layer = 0; layer < 2; ++layer) {
    for (int cc = 0; cc < nch; ++cc) {
      const int t0_fw = cc * TC;
      const int t0_bw = 512 - (cc + 1) * TC;
      const int mb_fw = t0_fw * 64;
      const int mb_bw = t0_bw * 64;
      dim3 g(16, CM / 128, 2);
      if (layer == 0)
        xg_gemm<512, 1><<<g, 256, 0, stream>>>(inputs, Wih[0][0], Wih[0][1],
                                               xg_fw, xg_bw, mb_fw, mb_bw);
      else
        xg_gemm<1024, 0><<<g, 256, 0, stream>>>(hs0, Wih[1][0], Wih[1][1],
                                                xg_fw, xg_bw, mb_fw, mb_bw);
      hipMemsetAsync(sync, 0, 4096, stream);
      lstm_rec<<<32, 128, 0, stream>>>(
          xg_fw, xg_bw, t0_fw, t0_bw,
          Whh[layer][0], Whh[layer][1],
          bih[layer][0], bhh[layer][0], bih[layer][1], bhh[layer][1],
          mask, hs0, outputs, layer,
          hn + layer * 65536, cn + layer * 65536,
          cstate, hglob, cc * TC, (cc + 1) * TC, sync);
    }
  }
}

// Round 8
// 21414.946 us; speedup vs baseline: 1.3989x; 1.0142x over previous
//
#include <hip/hip_runtime.h>
#include <stdint.h>

// 2-layer bidirectional LSTM, B=64 S=512 IN=512 H=512. I/O f32; MFMA operands bf16;
// gate math f32. Gate order i,f,g,o.
//
//  xg block layout: per dir, per (tt, wg) one contiguous 16KB block:
//    [q(4)][ct(2)][w(2)][mtl(2)][mgrp(4)][c16(16)][r(4)]  (bf16 elems)
//  recurrence: 32 real WGs (16/dir, 32 h-cols each, 2 waves) + 224 BALLAST WGs
//  (dependent-FMA spin to hold SCLK up; exit when slot[watched] reaches last step).
//  h exchange: coherent (sc0 sc1) stores to a 2-slot global ring; per step the WG
//  stages the 64KB h matrix into LDS (XOR-swizzled) via 2 batches of 16 coherent
//  dwordx4 loads/thread; MFMA A-frags via ds_read_b128.
//  barrier (NO RMW): WG stores step s to its own 64B slot (sc0 sc1); wave 0 polls
//  all 16 slots in parallel (lane i -> slot i, divergent-loop exit).
//
//  ws: [sync 4096B: 32 slots x 64B][hglob 2*2*64*512*2B][cstate (nch>1)]
//      [hs0 (nch>1; else aliased into d_out)][xg_fw][xg_bw]

typedef short bf16x8 __attribute__((ext_vector_type(8)));
typedef float f32x4 __attribute__((ext_vector_type(4)));
typedef unsigned short u16;

template<int N> struct IC { static constexpr int value = N; };

__device__ __forceinline__ float bf2f(u16 u) {
  union { uint32_t i; float f; } v; v.i = ((uint32_t)u) << 16; return v.f;
}
__device__ __forceinline__ u16 f2bf(float f) {
  union { float f; uint32_t i; } v; v.f = f;
  uint32_t u = v.i;
  return (u16)((u + 0x7FFFu + ((u >> 16) & 1u)) >> 16);
}
__device__ __forceinline__ float sigf(float x) { return 1.0f / (1.0f + __expf(-x)); }
__device__ __forceinline__ float tanhf_(float x) { return 2.0f / (1.0f + __expf(-2.0f * x)) - 1.0f; }
__device__ __forceinline__ u16 u4get(ushort4 v, int r) {
  return r == 0 ? v.x : r == 1 ? v.y : r == 2 ? v.z : v.w;
}
__device__ __forceinline__ bf16x8 ld8f32(const float* p) {
  float4 a = *(const float4*)p;
  float4 b = *(const float4*)(p + 4);
  bf16x8 r;
  r[0] = (short)f2bf(a.x); r[1] = (short)f2bf(a.y);
  r[2] = (short)f2bf(a.z); r[3] = (short)f2bf(a.w);
  r[4] = (short)f2bf(b.x); r[5] = (short)f2bf(b.y);
  r[6] = (short)f2bf(b.z); r[7] = (short)f2bf(b.w);
  return r;
}
// coherent (cross-XCD, bypass L1/L2) accesses
__device__ __forceinline__ void ldg_sc(bf16x8& d, const u16* p) {
  asm volatile("global_load_dwordx4 %0, %1, off sc0 sc1" : "=&v"(d) : "v"(p));
}
__device__ __forceinline__ void stg_sc16(u16* p, u16 v) {
  uint32_t vv = v;
  asm volatile("global_store_short %0, %1, off sc0 sc1" :: "v"(p), "v"(vv) : "memory");
}
__device__ __forceinline__ void stg_sc32(int* p, int v) {
  asm volatile("global_store_dword %0, %1, off sc0 sc1" :: "v"(p), "v"(v) : "memory");
}
__device__ __forceinline__ int ldg_sc32(const int* p) {
  int v;
  asm volatile("global_load_dword %0, %1, off sc0 sc1\n\ts_waitcnt vmcnt(0)"
               : "=v"(v) : "v"(p) : "memory");
  return v;
}
__device__ __forceinline__ void wait_vm0() {
  asm volatile("s_waitcnt vmcnt(0)" ::: "memory");
  __builtin_amdgcn_sched_barrier(0);
}

// ---------------- xg GEMM ----------------
// A[m][k] = Abuf[((m&63)*512 + (m>>6))*KDIM + k]; AF32=1: f32 (inputs), 0: bf16 (hs0).
// Output: per-(tt,wg) 16KB blocks. grid (16, CM/128, 2), block 256.
template<int KDIM, int AF32>
__global__ __launch_bounds__(256) void xg_gemm(
    const void* __restrict__ Av,
    const float* __restrict__ Wfw, const float* __restrict__ Wbw,
    u16* __restrict__ xgf, u16* __restrict__ xgb,
    int mb_fw, int mb_bw)
{
  const int tid = threadIdx.x;
  const int l = tid & 63, w = tid >> 6;
  const int wm = w & 1, wn = w >> 1;
  const int z = blockIdx.z;
  const float* W = z ? Wbw : Wfw;
  u16* xg = z ? xgb : xgf;
  const int m_base = z ? mb_bw : mb_fw;
  const int m0 = m_base + blockIdx.y * 128 + wm * 64;
  const int n0 = blockIdx.x * 128 + wn * 64;

  const float* Af = (const float*)Av;
  const u16*   Au = (const u16*)Av;
  long aoff[4];
#pragma unroll
  for (int mt = 0; mt < 4; ++mt) {
    int m = m0 + mt * 16 + (l & 15);
    aoff[mt] = ((long)(m & 63) * 512 + (m >> 6)) * KDIM + ((l >> 4) * 8);
  }
  const float* brow[4];
#pragma unroll
  for (int nt = 0; nt < 4; ++nt) {
    int n = n0 + nt * 16 + (l & 15);
    brow[nt] = W + (long)n * KDIM + ((l >> 4) * 8);
  }
  f32x4 acc[4][4] = {};
  for (int kk = 0; kk < KDIM / 32; ++kk) {
    bf16x8 a[4], b[4];
#pragma unroll
    for (int mt = 0; mt < 4; ++mt) {
      if constexpr (AF32) a[mt] = ld8f32(Af + aoff[mt] + kk * 32);
      else                a[mt] = *(const bf16x8*)(Au + aoff[mt] + kk * 32);
    }
#pragma unroll
    for (int nt = 0; nt < 4; ++nt) b[nt] = ld8f32(brow[nt] + kk * 32);
#pragma unroll
    for (int mt = 0; mt < 4; ++mt)
#pragma unroll
      for (int nt = 0; nt < 4; ++nt)
        acc[mt][nt] = __builtin_amdgcn_mfma_f32_16x16x32_bf16(a[mt], b[nt], acc[mt][nt], 0, 0, 0);
  }
  // store into block layout; D frag: n = n0+nt*16+(l&15), m = m0+mt*16+(l>>4)*4+r
  const int ttg = (m0 - m_base) >> 6;   // chunk-relative tt
#pragma unroll
  for (int nt = 0; nt < 4; ++nt) {
    const int nu = n0 + nt * 16;        // lane-uniform part of n
    const int q  = nu >> 9;
    const int wgi = (nu >> 5) & 15;
    const int ct  = (nu >> 4) & 1;
#pragma unroll
    for (int mt = 0; mt < 4; ++mt) {
      long boff = ((long)ttg * 16 + wgi) * 8192
                + q * 2048 + ct * 1024 + (mt >> 1) * 512 + (mt & 1) * 256
                + (l >> 4) * 64 + (l & 15) * 4;
      ushort4 u;
      u.x = f2bf(acc[mt][nt][0]); u.y = f2bf(acc[mt][nt][1]);
      u.z = f2bf(acc[mt][nt][2]); u.w = f2bf(acc[mt][nt][3]);
      *(ushort4*)(xg + boff) = u;
    }
  }
}

// ---------------- recurrence ----------------
// grid=256: blocks 0..31 real (d=blk>>4, wg=blk&15), 32..255 ballast.
__global__ __launch_bounds__(128, 1) void lstm_rec(
    const u16* __restrict__ xg_fw, const u16* __restrict__ xg_bw,
    int t0_fw, int t0_bw,
    const float* __restrict__ Whh_fw, const float* __restrict__ Whh_bw,
    const float* __restrict__ bih_fw, const float* __restrict__ bhh_fw,
    const float* __restrict__ bih_bw, const float* __restrict__ bhh_bw,
    const float* __restrict__ mask,
    u16* __restrict__ hs0, float* __restrict__ outF, int out_mode,
    float* __restrict__ hn, float* __restrict__ cn,
    float* __restrict__ cstate, u16* __restrict__ hglob,
    int t_begin, int t_end, int* __restrict__ sync)
{
  const int nsteps = t_end - t_begin;

  // ---------------- ballast WGs: hold SCLK up, exit when recurrence done ----------
  if (blockIdx.x >= 32) {
    if (nsteps < 2) return;
    const int target = nsteps - 1;
    const int* sp = sync + ((blockIdx.x & 31) * 16);
    float z0 = 1.0f, z1 = 1.1f, z2 = 1.2f, z3 = 1.3f;
    while (ldg_sc32(sp) < target) {
#pragma unroll 16
      for (int i = 0; i < 512; ++i) {
        z0 = __builtin_fmaf(z0, 1.0000001f, 1e-9f);
        z1 = __builtin_fmaf(z1, 1.0000001f, 1e-9f);
        z2 = __builtin_fmaf(z2, 1.0000001f, 1e-9f);
        z3 = __builtin_fmaf(z3, 1.0000001f, 1e-9f);
      }
      asm volatile("" : "+v"(z0), "+v"(z1), "+v"(z2), "+v"(z3));
    }
    return;
  }

  const int tid = threadIdx.x;
  const int l = tid & 63;
  const int w = tid >> 6;
  const int d = blockIdx.x >> 4;
  const int wg = blockIdx.x & 15;
  const int j0 = wg * 32;

  const float* Whh = d ? Whh_bw : Whh_fw;
  const float* bih = d ? bih_bw : bih_fw;
  const float* bhh = d ? bhh_bw : bhh_fw;
  const u16* xgd = d ? xg_bw : xg_fw;
  const int t0 = d ? t0_bw : t0_fw;
  u16* hg = hglob + d * 2 * 32768;          // [2 slots][64][512]
  int* myslot = sync + ((d * 16 + wg) * 16);          // own 64B line
  const int* pollbase = sync + ((d * 16 + (l & 15)) * 16);

  __shared__ float ex[2][2][2][2][4][64];   // exchange, 16KB
  __shared__ u16 hlds[32768];               // staged h, 64KB, XOR-swizzled rows

  // Whh fragments (bf16): B-op[k][n]=Whh[n][k]; lane: col=l&15, k=(l>>4)*8+j
  bf16x8 Bf[2][2][16];
#pragma unroll
  for (int g2 = 0; g2 < 2; ++g2) {
#pragma unroll
    for (int ct = 0; ct < 2; ++ct) {
      const int grow = (w * 2 + g2) * 512 + j0 + ct * 16 + (l & 15);
      const float* p = Whh + (long)grow * 512 + ((l >> 4) * 8);
#pragma unroll
      for (int kk = 0; kk < 16; ++kk)
        Bf[g2][ct][kk] = ld8f32(p + kk * 32);
    }
  }
  float bsum[4][2];
#pragma unroll
  for (int q = 0; q < 4; ++q)
#pragma unroll
    for (int ct = 0; ct < 2; ++ct) {
      int g = q * 512 + j0 + ct * 16 + (l & 15);
      bsum[q][ct] = bih[g] + bhh[g];
    }

  float c_[2][2][4];
  float hl[2][2][4];
#pragma unroll
  for (int ct = 0; ct < 2; ++ct)
#pragma unroll
    for (int mtl = 0; mtl < 2; ++mtl)
#pragma unroll
      for (int r = 0; r < 4; ++r) { c_[ct][mtl][r] = 0.f; hl[ct][mtl][r] = 0.f; }
  if (t_begin != 0) {
#pragma unroll
    for (int ct = 0; ct < 2; ++ct)
#pragma unroll
      for (int mtl = 0; mtl < 2; ++mtl)
#pragma unroll
        for (int r = 0; r < 4; ++r) {
          int brow = (w * 2 + mtl) * 16 + ((l >> 4) * 4) + r;
          int col = j0 + ct * 16 + (l & 15);
          c_[ct][mtl][r] = cstate[d * 32768 + brow * 512 + col];
        }
  }

  // xg + mask register prefetch; per-WG per-step block is contiguous 16KB
  ushort4 xv[4][2][2] = {}, xn[4][2][2] = {};
  float   mv[2][4] = {},    mn[2][4] = {};
  const int lo_off = (l >> 4) * 64 + (l & 15) * 4;
  auto ld_step = [&](int tt, ushort4 (&xd)[4][2][2], float (&md)[2][4]) {
    const u16* bp = xgd + ((long)(tt - t0) * 16 + wg) * 8192 + lo_off;
#pragma unroll
    for (int q = 0; q < 4; ++q)
#pragma unroll
      for (int ct = 0; ct < 2; ++ct)
#pragma unroll
        for (int mtl = 0; mtl < 2; ++mtl)
          xd[q][ct][mtl] = *(const ushort4*)(bp + q * 2048 + ct * 1024 + w * 512 + mtl * 256);
#pragma unroll
    for (int mtl = 0; mtl < 2; ++mtl)
#pragma unroll
      for (int r = 0; r < 4; ++r) {
        int brow = (w * 2 + mtl) * 16 + ((l >> 4) * 4) + r;
        md[mtl][r] = mask[brow * 512 + tt];
      }
  };
  ld_step(d ? (511 - t_begin) : t_begin, xv, mv);

  for (int t = t_begin; t < t_end; ++t) {
    const int tt = d ? (511 - t) : t;

    // ---- cooperative h stage: 64KB global (coherent) -> LDS, 2 batches of 16 ----
    if (t > 0) {
      const u16* hsrc = hg + (t & 1) * 32768;
#pragma unroll
      for (int bt = 0; bt < 2; ++bt) {
        bf16x8 tmp[16];
#pragma unroll
        for (int i = 0; i < 16; ++i) {
          int c = (bt * 16 + i) * 128 + tid;     // chunk 0..4095 (16B each)
          ldg_sc(tmp[i], hsrc + c * 8);
        }
        wait_vm0();
#pragma unroll
        for (int i = 0; i < 16; ++i) {
          int c = (bt * 16 + i) * 128 + tid;
          int row = c >> 6;                       // byte>>10
          int kb = (c & 63) * 16;                 // byte within row
          *(bf16x8*)((char*)hlds + row * 1024 + (kb ^ ((row & 7) << 4))) = tmp[i];
        }
      }
    }
    __syncthreads();

    f32x4 acc[2][2][4] = {};
    if (t > 0) {
#pragma unroll
      for (int kk = 0; kk < 16; ++kk) {
        bf16x8 a[4];
#pragma unroll
        for (int mt = 0; mt < 4; ++mt) {
          int r = (l & 15) + mt * 16;
          int kb = kk * 64 + (l >> 4) * 16;
          a[mt] = *(const bf16x8*)((const char*)hlds + r * 1024 + (kb ^ ((r & 7) << 4)));
        }
#pragma unroll
        for (int g2 = 0; g2 < 2; ++g2)
#pragma unroll
          for (int ct = 0; ct < 2; ++ct)
#pragma unroll
            for (int mt = 0; mt < 4; ++mt)
              acc[g2][ct][mt] = __builtin_amdgcn_mfma_f32_16x16x32_bf16(
                  a[mt], Bf[g2][ct][kk], acc[g2][ct][mt], 0, 0, 0);
      }
    }

    // cross-wave exchange: wave w hands its 2 gate quadrants for the OTHER row-half
    auto do_ex = [&](auto Wc) {
      constexpr int W = decltype(Wc)::value;
#pragma unroll
      for (int g2 = 0; g2 < 2; ++g2)
#pragma unroll
        for (int ct = 0; ct < 2; ++ct)
#pragma unroll
          for (int mtl = 0; mtl < 2; ++mtl)
#pragma unroll
            for (int r = 0; r < 4; ++r)
              ex[W][g2][ct][mtl][r][l] = acc[g2][ct][(W ^ 1) * 2 + mtl][r];
    };
    if (w == 0) do_ex(IC<0>{}); else do_ex(IC<1>{});
    __syncthreads();

    // prefetch NEXT step's xg/mask (immutable; overlaps pointwise + barrier)
    if (t + 1 < t_end) ld_step(d ? (511 - (t + 1)) : (t + 1), xn, mn);

    auto do_pw = [&](auto Wc) {
      constexpr int W = decltype(Wc)::value;
#pragma unroll
      for (int ct = 0; ct < 2; ++ct)
#pragma unroll
        for (int mtl = 0; mtl < 2; ++mtl)
#pragma unroll
          for (int r = 0; r < 4; ++r) {
            int brow = (W * 2 + mtl) * 16 + ((l >> 4) * 4) + r;
            float gv[4];
#pragma unroll
            for (int q = 0; q < 4; ++q) {
              float raw = ((q >> 1) == W)
                            ? acc[q & 1][ct][W * 2 + mtl][r]
                            : ex[W ^ 1][q & 1][ct][mtl][r][l];
              gv[q] = raw + bf2f(u4get(xv[q][ct][mtl], r)) + bsum[q][ct];
            }
            float iv = sigf(gv[0]);
            float fv = sigf(gv[1]);
            float gg = tanhf_(gv[2]);
            float ov = sigf(gv[3]);
            float cnew = fv * c_[ct][mtl][r] + iv * gg;
            float hnew = ov * tanhf_(cnew);
            float mvv = mv[mtl][r];
            float h2 = hnew * mvv;
            c_[ct][mtl][r] = cnew * mvv;
            hl[ct][mtl][r] = h2;
            int col = j0 + ct * 16 + (l & 15);
            u16 hb = f2bf(h2);
            stg_sc16(&hg[(((t + 1) & 1) * 64 + brow) * 512 + col], hb);
            if (out_mode == 0)
              hs0[((long)brow * 512 + tt) * 1024 + d * 512 + col] = hb;
            else
              outF[((long)brow * 512 + tt) * 1024 + d * 512 + col] = h2;
          }
    };
    if (w == 0) do_pw(IC<0>{}); else do_pw(IC<1>{});

    if (t < t_end - 1) {
      __syncthreads();   // drains all stores (sc h-stores acked at coherence point)
      const int s = t - t_begin + 1;
      if (tid == 0) stg_sc32(myslot, s);     // publish arrival (own line, no RMW)
      if (w == 0) {
        // lane i polls slot i (i<16; lanes 16..63 duplicate slot 0) — divergent-exit
        while (ldg_sc32(pollbase) < s) { }
      }
      __syncthreads();
#pragma unroll
      for (int q = 0; q < 4; ++q)
#pragma unroll
        for (int ct = 0; ct < 2; ++ct)
#pragma unroll
          for (int mtl = 0; mtl < 2; ++mtl) xv[q][ct][mtl] = xn[q][ct][mtl];
#pragma unroll
      for (int mtl = 0; mtl < 2; ++mtl)
#pragma unroll
        for (int r = 0; r < 4; ++r) mv[mtl][r] = mn[mtl][r];
    }
  }

  if (t_end < 512) {
#pragma unroll
    for (int ct = 0; ct < 2; ++ct)
#pragma unroll
      for (int mtl = 0; mtl < 2; ++mtl)
#pragma unroll
        for (int r = 0; r < 4; ++r) {
          int brow = (w * 2 + mtl) * 16 + ((l >> 4) * 4) + r;
          int col = j0 + ct * 16 + (l & 15);
          cstate[d * 32768 + brow * 512 + col] = c_[ct][mtl][r];
        }
  } else {
#pragma unroll
    for (int ct = 0; ct < 2; ++ct)
#pragma unroll
      for (int mtl = 0; mtl < 2; ++mtl)
#pragma unroll
        for (int r = 0; r < 4; ++r) {
          int brow = (w * 2 + mtl) * 16 + ((l >> 4) * 4) + r;
          int col = j0 + ct * 16 + (l & 15);
          hn[brow * 1024 + d * 512 + col] = hl[ct][mtl][r];
          cn[brow * 1024 + d * 512 + col] = c_[ct][mtl][r];
        }
  }
}

extern "C" void kernel_launch(void* const* d_in, const int* in_sizes, int n_in,
                              void* d_out, int out_size, void* d_ws, size_t ws_size,
                              hipStream_t stream) {
  const float* inputs = (const float*)d_in[0];
  const float* mask   = (const float*)d_in[1];
  const float* Wih[2][2] = { { (const float*)d_in[2],  (const float*)d_in[6]  },
                             { (const float*)d_in[10], (const float*)d_in[14] } };
  const float* Whh[2][2] = { { (const float*)d_in[3],  (const float*)d_in[7]  },
                             { (const float*)d_in[11], (const float*)d_in[15] } };
  const float* bih[2][2] = { { (const float*)d_in[4],  (const float*)d_in[8]  },
                             { (const float*)d_in[12], (const float*)d_in[16] } };
  const float* bhh[2][2] = { { (const float*)d_in[5],  (const float*)d_in[9]  },
                             { (const float*)d_in[13], (const float*)d_in[17] } };

  float* outputs = (float*)d_out;            // [64][512][1024] f32
  float* hn      = outputs + 33554432;       // [2][64][1024] f32
  float* cn      = hn + 131072;              // [2][64][1024] f32

  int nch = 0;
  for (int c : {1, 2, 4, 8, 16, 32}) {
    size_t xg_b = 2048UL * (32768 / c) * 2;   // per-dir chunk bytes
    size_t need = 4096 + 262144 + (c > 1 ? (262144UL + 67108864UL) : 0) + 2 * xg_b;
    if (ws_size >= need) { nch = c; break; }
  }
  if (!nch) {
    hipMemsetAsync(d_out, 0x49, 1024, stream);
    return;
  }
  const int TC = 512 / nch;
  const int CM = TC * 64;

  char* ws = (char*)d_ws;
  int*   sync   = (int*)ws;
  u16*   hglob  = (u16*)(ws + 4096);
  float* cstate = (float*)(ws + 4096 + 262144);
  u16*   hs0;
  u16*   xg_fw;
  if (nch > 1) {
    hs0   = (u16*)(ws + 4096 + 262144 + 262144);
    xg_fw = (u16*)(ws + 4096 + 262144 + 262144 + 67108864);
  } else {
    hs0   = (u16*)d_out;   // bf16 hs0 aliased into outputs region (GEMM precedes rec)
    xg_fw = (u16*)(ws + 4096 + 262144);
  }
  u16* xg_bw = xg_fw + 2048L * CM;

  for (int layer = 0; layer < 2; ++layer) {
    for (int cc = 0; cc < nch; ++cc) {
      const int t0_fw = cc * TC;
      const int t0_bw = 512 - (cc + 1) * TC;
      const int mb_fw = t0_fw * 64;
      const int mb_bw = t0_bw * 64;
      dim3 g(16, CM / 128, 2);
      if (layer == 0)
        xg_gemm<512, 1><<<g, 256, 0, stream>>>(inputs, Wih[0][0], Wih[0][1],
                                               xg_fw, xg_bw, mb_fw, mb_bw);
      else
        xg_gemm<1024, 0><<<g, 256, 0, stream>>>(hs0, Wih[1][0], Wih[1][1],
                                                xg_fw, xg_bw, mb_fw, mb_bw);
      hipMemsetAsync(sync, 0, 4096, stream);
      lstm_rec<<<256, 128, 0, stream>>>(
          xg_fw, xg_bw, t0_fw, t0_bw,
          Whh[layer][0], Whh[layer][1],
          bih[layer][0], bhh[layer][0], bih[layer][1], bhh[layer][1],
          mask, hs0, outputs, layer,
          hn + layer * 65536, cn + layer * 65536,
          cstate, hglob, cc * TC, (cc + 1) * TC, sync);
    }
  }
}

// Round 9
// 16782.921 us; speedup vs baseline: 1.7850x; 1.2760x over previous
//
#include <hip/hip_runtime.h>
#include <stdint.h>

// 2-layer bidirectional LSTM, B=64 S=512 IN=512 H=512. I/O f32; MFMA bf16; gates f32.
//
// Col-split recurrence v2: 8 WGs/dir x 256 thr (4 waves; wave w = gate q=w), 64 h-cols/WG.
//  - Whh slice register-resident (Bf[4ct][16kk] = 256 VGPR/wave).
//  - h ring hglob [d][slot2][wg8][row64][col64] bf16: stores 32B-contiguous coherent;
//    staging = ONE batch of 16x16B coherent loads/thread -> LDS XOR-swizzled.
//  - pointwise: thread = (row=l, cols w*16..+16); ex LDS pad-65; bias in LDS.
//  - barrier: per-WG slot store (sc) + wave0 lanes poll 8 slots; no RMW, no fences.
// xg layout: per (tt,wg) 32KB block [q4][row64][col64] bf16 (GEMM does LDS transpose).
// ws: [sync 4096B][hglob 262144B][cstate 262144B (nch>1)][hs0 67MB (nch>1)][xg_fw][xg_bw]

typedef short bf16x8 __attribute__((ext_vector_type(8)));
typedef float f32x4 __attribute__((ext_vector_type(4)));
typedef unsigned short u16;

__device__ __forceinline__ float bf2f(u16 u) {
  union { uint32_t i; float f; } v; v.i = ((uint32_t)u) << 16; return v.f;
}
__device__ __forceinline__ u16 f2bf(float f) {
  union { float f; uint32_t i; } v; v.f = f;
  uint32_t u = v.i;
  return (u16)((u + 0x7FFFu + ((u >> 16) & 1u)) >> 16);
}
__device__ __forceinline__ float sigf(float x) { return 1.0f / (1.0f + __expf(-x)); }
__device__ __forceinline__ float tanhf_(float x) { return 2.0f / (1.0f + __expf(-2.0f * x)) - 1.0f; }
__device__ __forceinline__ u16 u4get(ushort4 v, int r) {
  return r == 0 ? v.x : r == 1 ? v.y : r == 2 ? v.z : v.w;
}
__device__ __forceinline__ bf16x8 ld8f32(const float* p) {
  float4 a = *(const float4*)p;
  float4 b = *(const float4*)(p + 4);
  bf16x8 r;
  r[0] = (short)f2bf(a.x); r[1] = (short)f2bf(a.y);
  r[2] = (short)f2bf(a.z); r[3] = (short)f2bf(a.w);
  r[4] = (short)f2bf(b.x); r[5] = (short)f2bf(b.y);
  r[6] = (short)f2bf(b.z); r[7] = (short)f2bf(b.w);
  return r;
}
// coherent (cross-XCD) accesses
__device__ __forceinline__ void ldg_sc(bf16x8& d, const u16* p) {
  asm volatile("global_load_dwordx4 %0, %1, off sc0 sc1" : "=&v"(d) : "v"(p));
}
__device__ __forceinline__ void stg_sc8(u16* p, ushort4 v) {
  asm volatile("global_store_dwordx2 %0, %1, off sc0 sc1" :: "v"(p), "v"(v) : "memory");
}
__device__ __forceinline__ void stg_sc32(int* p, int v) {
  asm volatile("global_store_dword %0, %1, off sc0 sc1" :: "v"(p), "v"(v) : "memory");
}
__device__ __forceinline__ int ldg_sc32(const int* p) {
  int v;
  asm volatile("global_load_dword %0, %1, off sc0 sc1\n\ts_waitcnt vmcnt(0)"
               : "=v"(v) : "v"(p) : "memory");
  return v;
}
__device__ __forceinline__ void wait_vm0() {
  asm volatile("s_waitcnt vmcnt(0)" ::: "memory");
  __builtin_amdgcn_sched_barrier(0);
}

// ---------------- xg GEMM ----------------
// A[m][k] = Abuf[((m&63)*512 + (m>>6))*KDIM + k]; AF32=1: f32 (inputs), 0: bf16 (hs0).
// Out: per-(tt,wg8) 32KB blocks [q4][row=b 64][col64] bf16 via LDS transpose epilogue.
template<int KDIM, int AF32>
__global__ __launch_bounds__(256) void xg_gemm(
    const void* __restrict__ Av,
    const float* __restrict__ Wfw, const float* __restrict__ Wbw,
    u16* __restrict__ xgf, u16* __restrict__ xgb,
    int mb_fw, int mb_bw)
{
  __shared__ u16 tl[128 * 136];   // [m128][n128+pad], 8-col cells XOR-swizzled by m&7
  const int tid = threadIdx.x;
  const int l = tid & 63, w = tid >> 6;
  const int wm = w & 1, wn = w >> 1;
  const int z = blockIdx.z;
  const float* W = z ? Wbw : Wfw;
  u16* xg = z ? xgb : xgf;
  const int m_base = z ? mb_bw : mb_fw;
  const int m0 = m_base + blockIdx.y * 128 + wm * 64;
  const int n0 = blockIdx.x * 128 + wn * 64;

  const float* Af = (const float*)Av;
  const u16*   Au = (const u16*)Av;
  long aoff[4];
#pragma unroll
  for (int mt = 0; mt < 4; ++mt) {
    int m = m0 + mt * 16 + (l & 15);
    aoff[mt] = ((long)(m & 63) * 512 + (m >> 6)) * KDIM + ((l >> 4) * 8);
  }
  const float* brow[4];
#pragma unroll
  for (int nt = 0; nt < 4; ++nt) {
    int n = n0 + nt * 16 + (l & 15);
    brow[nt] = W + (long)n * KDIM + ((l >> 4) * 8);
  }
  f32x4 acc[4][4] = {};
  for (int kk = 0; kk < KDIM / 32; ++kk) {
    bf16x8 a[4], b[4];
#pragma unroll
    for (int mt = 0; mt < 4; ++mt) {
      if constexpr (AF32) a[mt] = ld8f32(Af + aoff[mt] + kk * 32);
      else                a[mt] = *(const bf16x8*)(Au + aoff[mt] + kk * 32);
    }
#pragma unroll
    for (int nt = 0; nt < 4; ++nt) b[nt] = ld8f32(brow[nt] + kk * 32);
#pragma unroll
    for (int mt = 0; mt < 4; ++mt)
#pragma unroll
      for (int nt = 0; nt < 4; ++nt)
        acc[mt][nt] = __builtin_amdgcn_mfma_f32_16x16x32_bf16(a[mt], b[nt], acc[mt][nt], 0, 0, 0);
  }
  // frags -> LDS (bf16), swizzled cells
#pragma unroll
  for (int nt = 0; nt < 4; ++nt) {
    int nl = wn * 64 + nt * 16 + (l & 15);
    int cell = nl >> 3, within = nl & 7;
#pragma unroll
    for (int mt = 0; mt < 4; ++mt) {
#pragma unroll
      for (int r = 0; r < 4; ++r) {
        int ml = wm * 64 + mt * 16 + (l >> 4) * 4 + r;
        tl[ml * 136 + ((cell ^ (ml & 7)) << 3) + within] = f2bf(acc[mt][nt][r]);
      }
    }
  }
  __syncthreads();
  // rows -> global, 32B contiguous per chunk
  const int ml = tid & 127, half = tid >> 7;
  const int ttg = (blockIdx.y * 128 + ml) >> 6;     // chunk-relative tt
  const int b_  = (blockIdx.y * 128 + ml) & 63;
#pragma unroll
  for (int i = 0; i < 4; ++i) {
    int ncol = half * 64 + i * 16;
    int c0 = ncol >> 3;
    int4 v0 = *(const int4*)&tl[ml * 136 + ((c0 ^ (ml & 7)) << 3)];
    int4 v1 = *(const int4*)&tl[ml * 136 + (((c0 + 1) ^ (ml & 7)) << 3)];
    int n_glob = blockIdx.x * 128 + ncol;
    int q = n_glob >> 9, wgi = (n_glob >> 6) & 7, col = n_glob & 63;
    u16* dst = xg + ((long)ttg * 8 + wgi) * 16384 + q * 4096 + b_ * 64 + col;
    *(int4*)dst = v0;
    *(int4*)(dst + 8) = v1;
  }
}

// ---------------- recurrence ----------------
// grid=16: d=blockIdx.x>>3, wg=blockIdx.x&7 (h-cols [wg*64, wg*64+64)); 256 thr, 4 waves.
__global__ __launch_bounds__(256, 1) void lstm_rec(
    const u16* __restrict__ xg_fw, const u16* __restrict__ xg_bw,
    int t0_fw, int t0_bw,
    const float* __restrict__ Whh_fw, const float* __restrict__ Whh_bw,
    const float* __restrict__ bih_fw, const float* __restrict__ bhh_fw,
    const float* __restrict__ bih_bw, const float* __restrict__ bhh_bw,
    const float* __restrict__ mask,
    u16* __restrict__ hs0, float* __restrict__ outF, int out_mode,
    float* __restrict__ hn, float* __restrict__ cn,
    float* __restrict__ cstate, u16* __restrict__ hglob,
    int t_begin, int t_end, int* __restrict__ sync)
{
  const int tid = threadIdx.x;
  const int l = tid & 63;
  const int w = tid >> 6;           // wave = gate quadrant
  const int d = blockIdx.x >> 3;
  const int wg = blockIdx.x & 7;
  const int j0 = wg * 64;

  const float* Whh = d ? Whh_bw : Whh_fw;
  const float* bih = d ? bih_bw : bih_fw;
  const float* bhh = d ? bhh_bw : bhh_fw;
  const u16* xgd = d ? xg_bw : xg_fw;
  const int t0 = d ? t0_bw : t0_fw;
  u16* hgd = hglob + d * 65536;     // [slot2][wg8][row64][col64]

  __shared__ u16   hl_lds[32768];   // h [row64][cell32^swz][8] bf16, 64KB
  __shared__ float exl[4 * 64 * 65];// gate acc [q][row][col(+pad)] f32, 66.5KB
  __shared__ float blds[256];       // bias [q4][col64]

  // Whh frags: wave w, gate row = w*512 + j0 + ct*16 + (l&15), k = kk*32 + (l>>4)*8
  bf16x8 Bf[4][16];
#pragma unroll
  for (int ct = 0; ct < 4; ++ct) {
    const float* p = Whh + (long)(w * 512 + j0 + ct * 16 + (l & 15)) * 512 + ((l >> 4) * 8);
#pragma unroll
    for (int kk = 0; kk < 16; ++kk)
      Bf[ct][kk] = ld8f32(p + kk * 32);
  }
  {
    int q = tid >> 6, col = tid & 63;
    blds[q * 64 + col] = bih[q * 512 + j0 + col] + bhh[q * 512 + j0 + col];
  }

  // pointwise assignment: row = l, cols pc0..pc0+16
  const int row = l;
  const int pc0 = w * 16;
  float c_[16], hl[16];
#pragma unroll
  for (int i = 0; i < 16; ++i) { c_[i] = 0.f; hl[i] = 0.f; }
  if (t_begin != 0) {
#pragma unroll
    for (int i = 0; i < 16; ++i)
      c_[i] = cstate[d * 32768 + row * 512 + j0 + pc0 + i];
  }
  __syncthreads();   // blds ready

  ushort4 xv[4][4];
  float mv_;
  auto ld_xv = [&](int tt) {
    const u16* bp = xgd + ((long)(tt - t0) * 8 + wg) * 16384 + row * 64 + pc0;
#pragma unroll
    for (int q = 0; q < 4; ++q)
#pragma unroll
      for (int h = 0; h < 4; ++h)
        xv[q][h] = *(const ushort4*)(bp + q * 4096 + h * 4);
    mv_ = mask[row * 512 + tt];
  };
  ld_xv(d ? (511 - t_begin) : t_begin);

  for (int t = t_begin; t < t_end; ++t) {
    const int tt = d ? (511 - t) : t;

    // ---- stage h: ONE batch of 16 coherent 16B loads/thread -> swizzled LDS ----
    if (t > 0) {
      const u16* hsrc = hgd + (t & 1) * 32768;
      bf16x8 tmp[16];
#pragma unroll
      for (int i = 0; i < 16; ++i) {
        int cid = i * 256 + tid;              // 0..4095
        int wgp = cid >> 9, rowc = (cid >> 3) & 63, colg = cid & 7;
        ldg_sc(tmp[i], hsrc + wgp * 4096 + rowc * 64 + colg * 8);
      }
      wait_vm0();
#pragma unroll
      for (int i = 0; i < 16; ++i) {
        int cid = i * 256 + tid;
        int wgp = cid >> 9, rowc = (cid >> 3) & 63, colg = cid & 7;
        int kc = wgp * 8 + colg;
        *(bf16x8*)((char*)hl_lds + rowc * 1024 + (((kc ^ (rowc & 7)) << 4))) = tmp[i];
      }
    }
    __syncthreads();

    f32x4 acc[4][4] = {};   // [mt][ct]
    if (t > 0) {
#pragma unroll
      for (int kk = 0; kk < 16; ++kk) {
        bf16x8 a[4];
#pragma unroll
        for (int mt = 0; mt < 4; ++mt) {
          int ra = mt * 16 + (l & 15);
          int kc = kk * 4 + (l >> 4);
          a[mt] = *(const bf16x8*)((const char*)hl_lds + ra * 1024 + ((kc ^ (ra & 7)) << 4));
        }
#pragma unroll
        for (int ct = 0; ct < 4; ++ct)
#pragma unroll
          for (int mt = 0; mt < 4; ++mt)
            acc[mt][ct] = __builtin_amdgcn_mfma_f32_16x16x32_bf16(
                a[mt], Bf[ct][kk], acc[mt][ct], 0, 0, 0);
      }
    }

    // ---- exchange: wave w publishes gate-w acc [row][col] ----
#pragma unroll
    for (int mt = 0; mt < 4; ++mt)
#pragma unroll
      for (int ct = 0; ct < 4; ++ct)
#pragma unroll
        for (int r = 0; r < 4; ++r)
          exl[w * 4160 + (mt * 16 + (l >> 4) * 4 + r) * 65 + ct * 16 + (l & 15)] =
              acc[mt][ct][r];
    __syncthreads();

    // ---- pointwise: thread = (row, 16 cols) ----
    u16 hb[16];
#pragma unroll
    for (int i = 0; i < 16; ++i) {
      int col = pc0 + i;
      float g0 = exl[0 * 4160 + row * 65 + col] + bf2f(u4get(xv[0][i >> 2], i & 3)) + blds[0 * 64 + col];
      float g1 = exl[1 * 4160 + row * 65 + col] + bf2f(u4get(xv[1][i >> 2], i & 3)) + blds[1 * 64 + col];
      float g2 = exl[2 * 4160 + row * 65 + col] + bf2f(u4get(xv[2][i >> 2], i & 3)) + blds[2 * 64 + col];
      float g3 = exl[3 * 4160 + row * 65 + col] + bf2f(u4get(xv[3][i >> 2], i & 3)) + blds[3 * 64 + col];
      float iv = sigf(g0), fv = sigf(g1), gg = tanhf_(g2), oo = sigf(g3);
      float cnew = fv * c_[i] + iv * gg;
      float h2 = oo * tanhf_(cnew) * mv_;
      c_[i] = cnew * mv_;
      hl[i] = h2;
      hb[i] = f2bf(h2);
    }
    // h ring store: 32B contiguous coherent (4 x dwordx2)
    {
      u16* hdst = hgd + ((t + 1) & 1) * 32768 + wg * 4096 + row * 64 + pc0;
#pragma unroll
      for (int h = 0; h < 4; ++h) {
        ushort4 v; v.x = hb[h*4]; v.y = hb[h*4+1]; v.z = hb[h*4+2]; v.w = hb[h*4+3];
        stg_sc8(hdst + h * 4, v);
      }
    }
    // sequence output
    if (out_mode == 0) {
      u16* o = hs0 + ((long)row * 512 + tt) * 1024 + d * 512 + j0 + pc0;
#pragma unroll
      for (int h = 0; h < 4; ++h) {
        ushort4 v; v.x = hb[h*4]; v.y = hb[h*4+1]; v.z = hb[h*4+2]; v.w = hb[h*4+3];
        *(ushort4*)(o + h * 4) = v;
      }
    } else {
      float* o = outF + ((long)row * 512 + tt) * 1024 + d * 512 + j0 + pc0;
#pragma unroll
      for (int h = 0; h < 4; ++h) {
        float4 v; v.x = bf2f(hb[h*4]); v.y = bf2f(hb[h*4+1]);
        v.z = bf2f(hb[h*4+2]); v.w = bf2f(hb[h*4+3]);
        // store full-precision h2 (not bf16-rounded) for final outputs:
        v.x = hl[h*4]; v.y = hl[h*4+1]; v.z = hl[h*4+2]; v.w = hl[h*4+3];
        *(float4*)(o + h * 4) = v;
      }
    }

    // ---- inter-WG step barrier (per dir): slot store + 8-slot parallel poll ----
    if (t < t_end - 1) {
      wait_vm0();           // per-wave: h ring stores acked at coherence point
      __syncthreads();
      const int s = t - t_begin + 1;
      if (tid == 0) stg_sc32(sync + (d * 8 + wg) * 16, s);
      if (w == 0 && l < 8) {
        while (ldg_sc32(sync + (d * 8 + l) * 16) < s) { }
      }
      __syncthreads();
      ld_xv(d ? (511 - (t + 1)) : (t + 1));   // prefetch next step (hidden under MFMA)
    }
  }

  if (t_end < 512) {
#pragma unroll
    for (int i = 0; i < 16; ++i)
      cstate[d * 32768 + row * 512 + j0 + pc0 + i] = c_[i];
  } else {
#pragma unroll
    for (int i = 0; i < 16; ++i) {
      hn[row * 1024 + d * 512 + j0 + pc0 + i] = hl[i];
      cn[row * 1024 + d * 512 + j0 + pc0 + i] = c_[i];
    }
  }
}

extern "C" void kernel_launch(void* const* d_in, const int* in_sizes, int n_in,
                              void* d_out, int out_size, void* d_ws, size_t ws_size,
                              hipStream_t stream) {
  const float* inputs = (const float*)d_in[0];
  const float* mask   = (const float*)d_in[1];
  const float* Wih[2][2] = { { (const float*)d_in[2],  (const float*)d_in[6]  },
                             { (const float*)d_in[10], (const float*)d_in[14] } };
  const float* Whh[2][2] = { { (const float*)d_in[3],  (const float*)d_in[7]  },
                             { (const float*)d_in[11], (const float*)d_in[15] } };
  const float* bih[2][2] = { { (const float*)d_in[4],  (const float*)d_in[8]  },
                             { (const float*)d_in[12], (const float*)d_in[16] } };
  const float* bhh[2][2] = { { (const float*)d_in[5],  (const float*)d_in[9]  },
                             { (const float*)d_in[13], (const float*)d_in[17] } };

  float* outputs = (float*)d_out;            // [64][512][1024] f32
  float* hn      = outputs + 33554432;       // [2][64][1024] f32
  float* cn      = hn + 131072;              // [2][64][1024] f32

  int nch = 0;
  for (int c : {1, 2, 4, 8, 16, 32}) {
    size_t xg_b = 2048UL * (32768 / c) * 2;   // per-dir chunk bytes
    size_t need = 4096 + 262144 + (c > 1 ? (262144UL + 67108864UL) : 0) + 2 * xg_b;
    if (ws_size >= need) { nch = c; break; }
  }
  if (!nch) {
    hipMemsetAsync(d_out, 0x49, 1024, stream);
    return;
  }
  const int TC = 512 / nch;
  const int CM = TC * 64;

  char* ws = (char*)d_ws;
  int*   sync   = (int*)ws;
  u16*   hglob  = (u16*)(ws + 4096);                 // [2][2][8][64][64] bf16
  float* cstate = (float*)(ws + 4096 + 262144);      // [2][64][512] f32 (nch>1)
  u16*   hs0;
  u16*   xg_fw;
  if (nch > 1) {
    hs0   = (u16*)(ws + 4096 + 262144 + 262144);
    xg_fw = (u16*)(ws + 4096 + 262144 + 262144 + 67108864);
  } else {
    hs0   = (u16*)d_out;   // bf16 hs0 aliased into outputs region (GEMM precedes rec)
    xg_fw = (u16*)(ws + 4096 + 262144);
  }
  u16* xg_bw = xg_fw + 2048L * CM;

  for (int layer = 0; layer < 2; ++layer) {
    for (int cc = 0; cc < nch; ++cc) {
      const int t0_fw = cc * TC;
      const int t0_bw = 512 - (cc + 1) * TC;
      const int mb_fw = t0_fw * 64;
      const int mb_bw = t0_bw * 64;
      dim3 g(16, CM / 128, 2);
      if (layer == 0)
        xg_gemm<512, 1><<<g, 256, 0, stream>>>(inputs, Wih[0][0], Wih[0][1],
                                               xg_fw, xg_bw, mb_fw, mb_bw);
      else
        xg_gemm<1024, 0><<<g, 256, 0, stream>>>(hs0, Wih[1][0], Wih[1][1],
                                                xg_fw, xg_bw, mb_fw, mb_bw);
      hipMemsetAsync(sync, 0, 4096, stream);
      lstm_rec<<<16, 256, 0, stream>>>(
          xg_fw, xg_bw, t0_fw, t0_bw,
          Whh[layer][0], Whh[layer][1],
          bih[layer][0], bhh[layer][0], bih[layer][1], bhh[layer][1],
          mask, hs0, outputs, layer,
          hn + layer * 65536, cn + layer * 65536,
          cstate, hglob, cc * TC, (cc + 1) * TC, sync);
    }
  }
}